// Round 10
// baseline (511.364 us; speedup 1.0000x reference)
//
#include <hip/hip_runtime.h>
#include <hip/hip_bf16.h>
#include <math.h>

#define EPS 1e-5f

typedef __attribute__((ext_vector_type(8))) short bf16x8;
typedef __attribute__((ext_vector_type(4))) float f32x4;

__device__ __forceinline__ unsigned short f2bf(float f) {
    unsigned u = __float_as_uint(f);
    unsigned r = (u + 0x7FFFu + ((u >> 16) & 1u)) >> 16;   // RNE
    return (unsigned short)r;
}
__device__ __forceinline__ unsigned f2bf2(float lo, float hi) {
    return (unsigned)f2bf(lo) | ((unsigned)f2bf(hi) << 16);
}
__device__ __forceinline__ float bf2f(unsigned short u) {
    return __uint_as_float((unsigned)u << 16);
}
__device__ __forceinline__ void bfu2(unsigned u, float& lo, float& hi) {
    lo = __uint_as_float(u << 16);
    hi = __uint_as_float(u & 0xFFFF0000u);
}

// ---------- weight pack: 9 matrices fp32 [128k x 128n] -> bf16 fragment order ----------
// packed[mat][kc][nt][lane][j] = W[k][n], k = kc*32+(lane>>4)*8+j, n = nt*16+(lane&15).
// Index-symmetric: serves as B-op fragment of W AND as A-op fragment of W^T.
__global__ __launch_bounds__(256) void pack_w9(const float* __restrict__ W0, const float* __restrict__ W1,
                                               const float* __restrict__ W2, const float* __restrict__ W3,
                                               const float* __restrict__ W4, const float* __restrict__ W5,
                                               const float* __restrict__ W6, const float* __restrict__ W7,
                                               const float* __restrict__ W8, unsigned short* __restrict__ out) {
    int t = blockIdx.x * 256 + threadIdx.x;
    if (t >= 9 * 16384) return;
    int mat = t >> 14, r = t & 16383;
    const float* W;
    switch (mat) {
        case 0: W = W0; break; case 1: W = W1; break; case 2: W = W2; break;
        case 3: W = W3; break; case 4: W = W4; break; case 5: W = W5; break;
        case 6: W = W6; break; case 7: W = W7; break; default: W = W8; break;
    }
    int j = r & 7, lane = (r >> 3) & 63, nt = (r >> 9) & 7, kc = r >> 12;
    int k = kc * 32 + (lane >> 4) * 8 + j;
    int n = nt * 16 + (lane & 15);
    out[t] = f2bf(W[k * 128 + n]);
}

// ---------- fp32 -> bf16 elementwise ----------
__global__ __launch_bounds__(256) void f32_to_bf16(const float* __restrict__ in,
                                                   unsigned short* __restrict__ out, int n4) {
    int i = blockIdx.x * 256 + threadIdx.x;
    if (i >= n4) return;
    float4 v = ((const float4*)in)[i];
    ushort4 o = make_ushort4(f2bf(v.x), f2bf(v.y), f2bf(v.z), f2bf(v.w));
    ((ushort4*)out)[i] = o;
}

// ---------- MFMA GEMM, operand-swapped (D = W^T @ h^T -> node-major lanes) ----------
// D[row=outc, col=node]: lane holds 4 consecutive out-channels of ONE node
// -> contiguous float4 / uint2 stores, no LDS epilogue needed.
template <int ACT, int WBF>
__global__ __launch_bounds__(256) void gemm_mfma(const unsigned short* __restrict__ Abf,
                                                 const unsigned short* __restrict__ Bp,
                                                 const float* __restrict__ bias,
                                                 float* __restrict__ C,
                                                 unsigned short* __restrict__ Cbf, int M) {
    int tid = threadIdx.x;
    int wave = tid >> 6, lane = tid & 63;
    int kg = lane >> 4, sl = lane & 15;
    int node = blockIdx.x * 64 + wave * 16 + sl;
    int nc = (node < M) ? node : (M - 1);
    const unsigned short* Aptr = Abf + (size_t)nc * 128 + kg * 8;
    f32x4 acc[8];
#pragma unroll
    for (int nt = 0; nt < 8; ++nt) acc[nt] = (f32x4)(0.f);
#pragma unroll
    for (int kc = 0; kc < 4; ++kc) {
        bf16x8 hfrag = *(const bf16x8*)(Aptr + kc * 32);
        const unsigned short* bp = Bp + (size_t)kc * 4096 + (size_t)lane * 8;
#pragma unroll
        for (int nt = 0; nt < 8; ++nt) {
            bf16x8 w = *(const bf16x8*)(bp + nt * 512);
            acc[nt] = __builtin_amdgcn_mfma_f32_16x16x32_bf16(w, hfrag, acc[nt], 0, 0, 0);
        }
    }
    if (node < M) {
        size_t base = (size_t)node * 128;
#pragma unroll
        for (int nt = 0; nt < 8; ++nt) {
            int oc = nt * 16 + kg * 4;
            float4 bb = *(const float4*)&bias[oc];
            float v0 = acc[nt][0] + bb.x, v1 = acc[nt][1] + bb.y;
            float v2 = acc[nt][2] + bb.z, v3 = acc[nt][3] + bb.w;
            if (ACT) { v0 = fmaxf(v0, 0.f); v1 = fmaxf(v1, 0.f);
                       v2 = fmaxf(v2, 0.f); v3 = fmaxf(v3, 0.f); }
            *(float4*)&C[base + oc] = make_float4(v0, v1, v2, v3);
            if (WBF) *(uint2*)&Cbf[base + oc] = make_uint2(f2bf2(v0, v1), f2bf2(v2, v3));
        }
    }
}

// ---------- fused 4-output MFMA GEMM, operand-swapped epilogue ----------
__global__ __launch_bounds__(256) void gemm_qkvs(const unsigned short* __restrict__ Abf,
                                                 const unsigned short* __restrict__ Bq,
                                                 const unsigned short* __restrict__ Bk,
                                                 const unsigned short* __restrict__ Bv,
                                                 const unsigned short* __restrict__ Bs,
                                                 const float* __restrict__ bq,
                                                 const float* __restrict__ bk,
                                                 const float* __restrict__ bv,
                                                 const float* __restrict__ bs,
                                                 unsigned short* __restrict__ qbf,
                                                 unsigned short* __restrict__ kvbf,
                                                 float* __restrict__ xr, int M) {
    int tid = threadIdx.x;
    int wave = tid >> 6, lane = tid & 63;
    int kg = lane >> 4, sl = lane & 15;
    int node = blockIdx.x * 64 + wave * 16 + sl;
    int nc = (node < M) ? node : (M - 1);
    const unsigned short* Aptr = Abf + (size_t)nc * 128 + kg * 8;
    f32x4 aq[8], ak[8], av[8], as_[8];
#pragma unroll
    for (int nt = 0; nt < 8; ++nt) { aq[nt] = (f32x4)(0.f); ak[nt] = (f32x4)(0.f);
                                     av[nt] = (f32x4)(0.f); as_[nt] = (f32x4)(0.f); }
#pragma unroll
    for (int kc = 0; kc < 4; ++kc) {
        bf16x8 hfrag = *(const bf16x8*)(Aptr + kc * 32);
        size_t boff = (size_t)kc * 4096 + (size_t)lane * 8;
#pragma unroll
        for (int nt = 0; nt < 8; ++nt) {
            bf16x8 w0 = *(const bf16x8*)(Bq + boff + nt * 512);
            aq[nt] = __builtin_amdgcn_mfma_f32_16x16x32_bf16(w0, hfrag, aq[nt], 0, 0, 0);
            bf16x8 w1 = *(const bf16x8*)(Bk + boff + nt * 512);
            ak[nt] = __builtin_amdgcn_mfma_f32_16x16x32_bf16(w1, hfrag, ak[nt], 0, 0, 0);
            bf16x8 w2 = *(const bf16x8*)(Bv + boff + nt * 512);
            av[nt] = __builtin_amdgcn_mfma_f32_16x16x32_bf16(w2, hfrag, av[nt], 0, 0, 0);
            bf16x8 w3 = *(const bf16x8*)(Bs + boff + nt * 512);
            as_[nt] = __builtin_amdgcn_mfma_f32_16x16x32_bf16(w3, hfrag, as_[nt], 0, 0, 0);
        }
    }
    if (node < M) {
        size_t qb = (size_t)node * 128, kvb = (size_t)node * 256;
#pragma unroll
        for (int nt = 0; nt < 8; ++nt) {
            int oc = nt * 16 + kg * 4;
            float4 b0 = *(const float4*)&bq[oc];
            *(uint2*)&qbf[qb + oc] = make_uint2(f2bf2(aq[nt][0] + b0.x, aq[nt][1] + b0.y),
                                                f2bf2(aq[nt][2] + b0.z, aq[nt][3] + b0.w));
            float4 b1 = *(const float4*)&bk[oc];
            *(uint2*)&kvbf[kvb + oc] = make_uint2(f2bf2(ak[nt][0] + b1.x, ak[nt][1] + b1.y),
                                                  f2bf2(ak[nt][2] + b1.z, ak[nt][3] + b1.w));
            float4 b2 = *(const float4*)&bv[oc];
            *(uint2*)&kvbf[kvb + 128 + oc] = make_uint2(f2bf2(av[nt][0] + b2.x, av[nt][1] + b2.y),
                                                        f2bf2(av[nt][2] + b2.z, av[nt][3] + b2.w));
            float4 b3 = *(const float4*)&bs[oc];
            *(float4*)&xr[qb + oc] = make_float4(as_[nt][0] + b3.x, as_[nt][1] + b3.y,
                                                 as_[nt][2] + b3.z, as_[nt][3] + b3.w);
        }
    }
}

// ---------- CSR build ----------
__global__ __launch_bounds__(256) void csr_hist(const int* __restrict__ ei,
                                                int* __restrict__ deg, int E) {
    int e = blockIdx.x * 256 + threadIdx.x;
    if (e < E) atomicAdd(&deg[ei[E + e]], 1);
}

__global__ __launch_bounds__(256) void scan_block_sums(const int* __restrict__ deg,
                                                       int* __restrict__ bsums, int N) {
    __shared__ int sd[256];
    int i = blockIdx.x * 256 + threadIdx.x;
    sd[threadIdx.x] = (i < N) ? deg[i] : 0;
    __syncthreads();
    for (int off = 128; off > 0; off >>= 1) {
        if (threadIdx.x < off) sd[threadIdx.x] += sd[threadIdx.x + off];
        __syncthreads();
    }
    if (threadIdx.x == 0) bsums[blockIdx.x] = sd[0];
}

__global__ __launch_bounds__(256) void scan_bsums(const int* __restrict__ bsums,
                                                  int* __restrict__ boff, int nb) {
    __shared__ int sd[256];
    int tid = threadIdx.x;
    int per = (nb + 255) / 256;
    int start = tid * per;
    int s = 0;
    for (int i = 0; i < per; ++i) {
        int idx = start + i;
        if (idx < nb) s += bsums[idx];
    }
    int my = s;
    sd[tid] = s;
    __syncthreads();
    for (int off = 1; off < 256; off <<= 1) {
        int t = (tid >= off) ? sd[tid - off] : 0;
        __syncthreads();
        sd[tid] += t;
        __syncthreads();
    }
    int run = sd[tid] - my;
    for (int i = 0; i < per; ++i) {
        int idx = start + i;
        if (idx < nb) {
            boff[idx] = run;
            run += bsums[idx];
        }
    }
}

__global__ __launch_bounds__(256) void scan_local(const int* __restrict__ deg,
                                                  const int* __restrict__ boff,
                                                  int* __restrict__ rowptr,
                                                  int* __restrict__ wrptr, int N, int E) {
    __shared__ int sd[256];
    int i = blockIdx.x * 256 + threadIdx.x;
    int v = (i < N) ? deg[i] : 0;
    sd[threadIdx.x] = v;
    __syncthreads();
    for (int off = 1; off < 256; off <<= 1) {
        int t = (threadIdx.x >= off) ? sd[threadIdx.x - off] : 0;
        __syncthreads();
        sd[threadIdx.x] += t;
        __syncthreads();
    }
    if (i < N) {
        int excl = sd[threadIdx.x] - v + boff[blockIdx.x];
        rowptr[i] = excl;
        wrptr[i] = excl;
        if (i == N - 1) rowptr[N] = E;
    }
}

__global__ __launch_bounds__(256) void csr_fill(const int* __restrict__ ei,
                                                const float* __restrict__ ea,
                                                int* __restrict__ wrptr,
                                                int* __restrict__ csr_src,
                                                float* __restrict__ csr_w, int E) {
    int e = blockIdx.x * 256 + threadIdx.x;
    if (e >= E) return;
    int tgt = ei[E + e];
    int pos = atomicAdd(&wrptr[tgt], 1);
    csr_src[pos] = ei[e];
    csr_w[pos] = ea[e];
}

// ---------- attention gather v3: 16 lanes per node (4 nodes/wave), no online max ----------
__global__ __launch_bounds__(256) void attn_gather(const unsigned short* __restrict__ qbf,
                                                   const unsigned short* __restrict__ kvbf,
                                                   const float* __restrict__ xr,
                                                   const int* __restrict__ rowptr,
                                                   const int* __restrict__ csr_src,
                                                   const float* __restrict__ csr_w,
                                                   const float* __restrict__ Wel,
                                                   const float* __restrict__ Wb,
                                                   float* __restrict__ out, int N) {
    int tid = threadIdx.x;
    int n = blockIdx.x * 16 + (tid >> 4);
    int sl = tid & 15;
    bool live = (n < N);
    int nn = live ? n : (N - 1);

    uint4 qu = ((const uint4*)(qbf + (size_t)nn * 128))[sl];
    float qf[8];
    bfu2(qu.x, qf[0], qf[1]); bfu2(qu.y, qf[2], qf[3]);
    bfu2(qu.z, qf[4], qf[5]); bfu2(qu.w, qf[6], qf[7]);
    float wef[8];
    {
        float4 w0 = ((const float4*)Wel)[sl * 2];
        float4 w1 = ((const float4*)Wel)[sl * 2 + 1];
        wef[0] = w0.x; wef[1] = w0.y; wef[2] = w0.z; wef[3] = w0.w;
        wef[4] = w1.x; wef[5] = w1.y; wef[6] = w1.z; wef[7] = w1.w;
    }
    float qwe = 0.f;
#pragma unroll
    for (int c = 0; c < 8; ++c) qwe += qf[c] * wef[c];
    qwe += __shfl_xor(qwe, 1);
    qwe += __shfl_xor(qwe, 2);

    float l = 0.f;
    float acc[8];
#pragma unroll
    for (int c = 0; c < 8; ++c) acc[c] = 0.f;

    int beg = live ? rowptr[nn] : 0;
    int end = live ? rowptr[nn + 1] : 0;
    int i = beg;
    if (i < end) {
        float w = csr_w[i];
        const uint4* kvr = (const uint4*)(kvbf + (size_t)csr_src[i] * 256);
        uint4 ku = kvr[sl];
        uint4 vu = kvr[16 + sl];
        for (;;) {
            float wc = w;
            uint4 kuc = ku, vuc = vu;
            ++i;
            bool more = (i < end);
            if (more) {
                float w2 = csr_w[i];
                const uint4* kvr2 = (const uint4*)(kvbf + (size_t)csr_src[i] * 256);
                ku = kvr2[sl];
                vu = kvr2[16 + sl];
                w = w2;
            }
            float kf[8];
            bfu2(kuc.x, kf[0], kf[1]); bfu2(kuc.y, kf[2], kf[3]);
            bfu2(kuc.z, kf[4], kf[5]); bfu2(kuc.w, kf[6], kf[7]);
            float d = 0.f;
#pragma unroll
            for (int c = 0; c < 8; ++c) d += qf[c] * kf[c];
            d += __shfl_xor(d, 1);
            d += __shfl_xor(d, 2);
            float p = __expf((d + wc * qwe) * 0.17677669529663687f);
            l += p;
            float vf[8];
            bfu2(vuc.x, vf[0], vf[1]); bfu2(vuc.y, vf[2], vf[3]);
            bfu2(vuc.z, vf[4], vf[5]); bfu2(vuc.w, vf[6], vf[7]);
#pragma unroll
            for (int c = 0; c < 8; ++c)
                acc[c] += p * (vf[c] + wc * wef[c]);
            if (!more) break;
        }
    }

    float inv = (l > 0.f) ? 1.f / l : 0.f;
    float ox[8];
#pragma unroll
    for (int c = 0; c < 8; ++c) ox[c] = acc[c] * inv;

    const float* xrow = xr + (size_t)nn * 128;
    float4 a0 = ((const float4*)xrow)[sl * 2];
    float4 a1 = ((const float4*)xrow)[sl * 2 + 1];
    float xv[8] = {a0.x, a0.y, a0.z, a0.w, a1.x, a1.y, a1.z, a1.w};
    float4 b0 = ((const float4*)Wb)[sl * 2];
    float4 b1 = ((const float4*)Wb)[sl * 2 + 1];
    float4 c0 = ((const float4*)(Wb + 128))[sl * 2];
    float4 c1 = ((const float4*)(Wb + 128))[sl * 2 + 1];
    float4 d0 = ((const float4*)(Wb + 256))[sl * 2];
    float4 d1 = ((const float4*)(Wb + 256))[sl * 2 + 1];
    float wb0[8] = {b0.x, b0.y, b0.z, b0.w, b1.x, b1.y, b1.z, b1.w};
    float wb1[8] = {c0.x, c0.y, c0.z, c0.w, c1.x, c1.y, c1.z, c1.w};
    float wb2[8] = {d0.x, d0.y, d0.z, d0.w, d1.x, d1.y, d1.z, d1.w};
    float part = 0.f;
#pragma unroll
    for (int c = 0; c < 8; ++c)
        part += ox[c] * wb0[c] + xv[c] * wb1[c] + (ox[c] - xv[c]) * wb2[c];
    part += __shfl_xor(part, 1); part += __shfl_xor(part, 2);
    part += __shfl_xor(part, 4); part += __shfl_xor(part, 8);
    float beta = 1.f / (1.f + __expf(-part));

    if (live) {
        float4 r0, r1;
        r0.x = beta * xv[0] + (1.f - beta) * ox[0];
        r0.y = beta * xv[1] + (1.f - beta) * ox[1];
        r0.z = beta * xv[2] + (1.f - beta) * ox[2];
        r0.w = beta * xv[3] + (1.f - beta) * ox[3];
        r1.x = beta * xv[4] + (1.f - beta) * ox[4];
        r1.y = beta * xv[5] + (1.f - beta) * ox[5];
        r1.z = beta * xv[6] + (1.f - beta) * ox[6];
        r1.w = beta * xv[7] + (1.f - beta) * ox[7];
        ((float4*)(out + (size_t)n * 128))[sl * 2] = r0;
        ((float4*)(out + (size_t)n * 128))[sl * 2 + 1] = r1;
    }
}

// ---------- BN stats ----------
__global__ __launch_bounds__(256) void bn_stats(const float* __restrict__ o,
                                                float* __restrict__ bsum,
                                                float* __restrict__ bsumsq, int N) {
    int c = threadIdx.x & 127;
    int half = threadIdx.x >> 7;
    float s = 0.f, ss = 0.f;
    for (int r = blockIdx.x * 2 + half; r < N; r += gridDim.x * 2) {
        float val = o[(size_t)r * 128 + c];
        s += val; ss += val * val;
    }
    __shared__ float sd[2][128], sd2[2][128];
    sd[half][c] = s; sd2[half][c] = ss;
    __syncthreads();
    if (threadIdx.x < 128) {
        atomicAdd(&bsum[c], sd[0][c] + sd[1][c]);
        atomicAdd(&bsumsq[c], sd2[0][c] + sd2[1][c]);
    }
}

// ---------- BN apply + ReLU + residual (+ optional bf16 side-write) ----------
__global__ __launch_bounds__(256) void bn_apply(const float* __restrict__ o,
                                                const float* __restrict__ hres,
                                                float* __restrict__ hout,
                                                unsigned short* __restrict__ hout_bf,
                                                const float* __restrict__ bsum,
                                                const float* __restrict__ bsumsq,
                                                const float* __restrict__ gamma,
                                                const float* __restrict__ bbeta,
                                                int N, float invN) {
    int i = blockIdx.x * 256 + threadIdx.x;
    if (i >= N * 32) return;
    int c4 = i & 31;
    float4 s = ((const float4*)bsum)[c4];
    float4 ss = ((const float4*)bsumsq)[c4];
    float4 g = ((const float4*)gamma)[c4];
    float4 b = ((const float4*)bbeta)[c4];
    float4 ov = ((const float4*)o)[i];
    float4 hr = ((const float4*)hres)[i];
    float4 r;
    { float mu = s.x * invN, var = ss.x * invN - mu * mu;
      r.x = fmaxf((ov.x - mu) * (g.x * rsqrtf(var + EPS)) + b.x, 0.f) + hr.x; }
    { float mu = s.y * invN, var = ss.y * invN - mu * mu;
      r.y = fmaxf((ov.y - mu) * (g.y * rsqrtf(var + EPS)) + b.y, 0.f) + hr.y; }
    { float mu = s.z * invN, var = ss.z * invN - mu * mu;
      r.z = fmaxf((ov.z - mu) * (g.z * rsqrtf(var + EPS)) + b.z, 0.f) + hr.z; }
    { float mu = s.w * invN, var = ss.w * invN - mu * mu;
      r.w = fmaxf((ov.w - mu) * (g.w * rsqrtf(var + EPS)) + b.w, 0.f) + hr.w; }
    ((float4*)hout)[i] = r;
    if (hout_bf) {
        ushort4 ob = make_ushort4(f2bf(r.x), f2bf(r.y), f2bf(r.z), f2bf(r.w));
        ((ushort4*)hout_bf)[i] = ob;
    }
}

extern "C" void kernel_launch(void* const* d_in, const int* in_sizes, int n_in,
                              void* d_out, int out_size, void* d_ws, size_t ws_size,
                              hipStream_t stream) {
    const float* x     = (const float*)d_in[0];
    const int*   ei    = (const int*)d_in[1];
    const float* ea    = (const float*)d_in[2];
    const float* W_in  = (const float*)d_in[3];
    const float* b_in  = (const float*)d_in[4];
    const float* Wq    = (const float*)d_in[5];
    const float* bq    = (const float*)d_in[6];
    const float* Wk    = (const float*)d_in[7];
    const float* bk    = (const float*)d_in[8];
    const float* Wv    = (const float*)d_in[9];
    const float* bv    = (const float*)d_in[10];
    const float* We    = (const float*)d_in[11];
    const float* Wskip = (const float*)d_in[12];
    const float* bskip = (const float*)d_in[13];
    const float* Wbeta = (const float*)d_in[14];
    const float* bn_g  = (const float*)d_in[15];
    const float* bn_b  = (const float*)d_in[16];

    const int N = in_sizes[0] / 128;
    const int E = in_sizes[1] / 2;

    float* ws = (float*)d_ws;
    unsigned short* Bpack = (unsigned short*)ws;           // 9*16384 bf16 = 73728 floats
    size_t off = 73728;
    unsigned short* xbf  = (unsigned short*)(ws + off);               off += (size_t)N * 64;
    unsigned short* hbf  = (unsigned short*)(ws + off);               off += (size_t)N * 64;
    unsigned short* qbf  = (unsigned short*)(ws + off);               off += (size_t)N * 64;
    unsigned short* kvbf = (unsigned short*)(ws + off);               off += (size_t)N * 128;
    float* h    = ws + off;  off += (size_t)N * 128;
    float* xr   = ws + off;  off += (size_t)N * 128;
    float* attn = ws + off;  off += (size_t)N * 128;
    float* bnsum   = ws + off;  off += 128;
    float* bnsumsq = ws + off;  off += 128;
    float* csr_w   = ws + off;  off += (size_t)E;
    int* deg     = (int*)(ws + off);
    int* rowptr  = deg + N;
    int* wrptr   = rowptr + (N + 1);
    int* csr_src = wrptr + N;
    int* bsums   = csr_src + E;
    int* boff    = bsums + ((N + 255) / 256 + 1);

    dim3 blk(256);
    int gGemm   = (N + 63) / 64;
    int gNode16 = (N + 15) / 16;
    int gEdge   = (E + 255) / 256;
    int gApply  = (N * 32 + 255) / 256;
    int nbScan  = (N + 255) / 256;

    // ---- weight pack + x convert ----
    pack_w9<<<(9 * 16384 + 255) / 256, blk, 0, stream>>>(
        W_in, Wq, Wk, Wv, Wskip, Wq + 16384, Wk + 16384, Wv + 16384, Wskip + 16384, Bpack);
    f32_to_bf16<<<gApply, blk, 0, stream>>>(x, xbf, N * 32);

    // ---- CSR build ----
    hipMemsetAsync(deg, 0, (size_t)N * sizeof(int), stream);
    csr_hist<<<gEdge, blk, 0, stream>>>(ei, deg, E);
    scan_block_sums<<<nbScan, blk, 0, stream>>>(deg, bsums, N);
    scan_bsums<<<1, blk, 0, stream>>>(bsums, boff, nbScan);
    scan_local<<<nbScan, blk, 0, stream>>>(deg, boff, rowptr, wrptr, N, E);
    csr_fill<<<gEdge, blk, 0, stream>>>(ei, ea, wrptr, csr_src, csr_w, E);

    // ---- input projection (writes h fp32 + hbf bf16) ----
    gemm_mfma<1, 1><<<gGemm, blk, 0, stream>>>(xbf, Bpack + 0 * 16384, b_in, h, hbf, N);

    for (int l = 0; l < 2; ++l) {
        const unsigned short* Bq = Bpack + (size_t)(1 + l * 4 + 0) * 16384;
        const unsigned short* Bk = Bpack + (size_t)(1 + l * 4 + 1) * 16384;
        const unsigned short* Bv = Bpack + (size_t)(1 + l * 4 + 2) * 16384;
        const unsigned short* Bs = Bpack + (size_t)(1 + l * 4 + 3) * 16384;
        gemm_qkvs<<<gGemm, blk, 0, stream>>>(hbf, Bq, Bk, Bv, Bs,
                                             bq + l * 128, bk + l * 128, bv + l * 128, bskip + l * 128,
                                             qbf, kvbf, xr, N);
        attn_gather<<<gNode16, blk, 0, stream>>>(qbf, kvbf, xr, rowptr, csr_src, csr_w,
                                                 We + l * 128, Wbeta + l * 384, attn, N);
        hipMemsetAsync(bnsum, 0, 256 * sizeof(float), stream);
        bn_stats<<<512, blk, 0, stream>>>(attn, bnsum, bnsumsq, N);
        bn_apply<<<gApply, blk, 0, stream>>>(attn, h, (l == 1) ? (float*)d_out : h,
                                             (l == 0) ? hbf : (unsigned short*)0,
                                             bnsum, bnsumsq, bn_g + l * 128, bn_b + l * 128,
                                             N, 1.0f / (float)N);
    }
}

// Round 11
// 362.207 us; speedup vs baseline: 1.4118x; 1.4118x over previous
//
#include <hip/hip_runtime.h>
#include <hip/hip_bf16.h>
#include <math.h>

#define EPS 1e-5f

typedef __attribute__((ext_vector_type(8))) short bf16x8;
typedef __attribute__((ext_vector_type(4))) float f32x4;

__device__ __forceinline__ unsigned short f2bf(float f) {
    unsigned u = __float_as_uint(f);
    unsigned r = (u + 0x7FFFu + ((u >> 16) & 1u)) >> 16;   // RNE
    return (unsigned short)r;
}
__device__ __forceinline__ float bf2f(unsigned short u) {
    return __uint_as_float((unsigned)u << 16);
}
__device__ __forceinline__ void bfu2(unsigned u, float& lo, float& hi) {
    lo = __uint_as_float(u << 16);
    hi = __uint_as_float(u & 0xFFFF0000u);
}

// ---------- weight pack: 9 matrices fp32 [128k x 128n] -> bf16 B-fragment order ----------
__global__ __launch_bounds__(256) void pack_w9(const float* __restrict__ W0, const float* __restrict__ W1,
                                               const float* __restrict__ W2, const float* __restrict__ W3,
                                               const float* __restrict__ W4, const float* __restrict__ W5,
                                               const float* __restrict__ W6, const float* __restrict__ W7,
                                               const float* __restrict__ W8, unsigned short* __restrict__ out) {
    int t = blockIdx.x * 256 + threadIdx.x;
    if (t >= 9 * 16384) return;
    int mat = t >> 14, r = t & 16383;
    const float* W;
    switch (mat) {
        case 0: W = W0; break; case 1: W = W1; break; case 2: W = W2; break;
        case 3: W = W3; break; case 4: W = W4; break; case 5: W = W5; break;
        case 6: W = W6; break; case 7: W = W7; break; default: W = W8; break;
    }
    int j = r & 7, lane = (r >> 3) & 63, nt = (r >> 9) & 7, kc = r >> 12;
    int k = kc * 32 + (lane >> 4) * 8 + j;
    int n = nt * 16 + (lane & 15);
    out[t] = f2bf(W[k * 128 + n]);
}

// ---------- fp32 -> bf16 elementwise ----------
__global__ __launch_bounds__(256) void f32_to_bf16(const float* __restrict__ in,
                                                   unsigned short* __restrict__ out, int n4) {
    int i = blockIdx.x * 256 + threadIdx.x;
    if (i >= n4) return;
    float4 v = ((const float4*)in)[i];
    ushort4 o = make_ushort4(f2bf(v.x), f2bf(v.y), f2bf(v.z), f2bf(v.w));
    ((ushort4*)out)[i] = o;
}

// ---------- MFMA GEMM (round-8 version: direct stores; R9 LDS / R10 swap both regressed) ----------
template <int ACT, int WBF>
__global__ __launch_bounds__(256) void gemm_mfma(const unsigned short* __restrict__ Abf,
                                                 const unsigned short* __restrict__ Bp,
                                                 const float* __restrict__ bias,
                                                 float* __restrict__ C,
                                                 unsigned short* __restrict__ Cbf, int M) {
    int wave = threadIdx.x >> 6, lane = threadIdx.x & 63;
    int base = blockIdx.x * 64 + wave * 16;
    int m = lane & 15, kg = lane >> 4;
    int arow = base + m; if (arow >= M) arow = M - 1;
    const unsigned short* Aptr = Abf + (size_t)arow * 128 + kg * 8;
    f32x4 acc[8];
#pragma unroll
    for (int nt = 0; nt < 8; ++nt) acc[nt] = (f32x4)(0.f);
#pragma unroll
    for (int kc = 0; kc < 4; ++kc) {
        bf16x8 a = *(const bf16x8*)(Aptr + kc * 32);
        const unsigned short* bp = Bp + (size_t)kc * 4096 + (size_t)lane * 8;
#pragma unroll
        for (int nt = 0; nt < 8; ++nt) {
            bf16x8 b = *(const bf16x8*)(bp + nt * 512);
            acc[nt] = __builtin_amdgcn_mfma_f32_16x16x32_bf16(a, b, acc[nt], 0, 0, 0);
        }
    }
    int col0 = lane & 15;
    int r0 = base + (lane >> 4) * 4;
#pragma unroll
    for (int nt = 0; nt < 8; ++nt) {
        float bb = bias[nt * 16 + col0];
#pragma unroll
        for (int r = 0; r < 4; ++r) {
            int ro = r0 + r;
            if (ro < M) {
                float val = acc[nt][r] + bb;
                if (ACT) val = fmaxf(val, 0.f);
                C[(size_t)ro * 128 + nt * 16 + col0] = val;
                if (WBF) Cbf[(size_t)ro * 128 + nt * 16 + col0] = f2bf(val);
            }
        }
    }
}

// ---------- fused 4-output MFMA GEMM (round-8 version) ----------
__global__ __launch_bounds__(256) void gemm_qkvs(const unsigned short* __restrict__ Abf,
                                                 const unsigned short* __restrict__ Bq,
                                                 const unsigned short* __restrict__ Bk,
                                                 const unsigned short* __restrict__ Bv,
                                                 const unsigned short* __restrict__ Bs,
                                                 const float* __restrict__ bq,
                                                 const float* __restrict__ bk,
                                                 const float* __restrict__ bv,
                                                 const float* __restrict__ bs,
                                                 unsigned short* __restrict__ qbf,
                                                 unsigned short* __restrict__ kvbf,
                                                 float* __restrict__ xr, int M) {
    int wave = threadIdx.x >> 6, lane = threadIdx.x & 63;
    int base = blockIdx.x * 64 + wave * 16;
    int m = lane & 15, kg = lane >> 4;
    int arow = base + m; if (arow >= M) arow = M - 1;
    const unsigned short* Aptr = Abf + (size_t)arow * 128 + kg * 8;
    f32x4 aq[8], ak[8], av[8], as_[8];
#pragma unroll
    for (int nt = 0; nt < 8; ++nt) { aq[nt] = (f32x4)(0.f); ak[nt] = (f32x4)(0.f);
                                     av[nt] = (f32x4)(0.f); as_[nt] = (f32x4)(0.f); }
#pragma unroll
    for (int kc = 0; kc < 4; ++kc) {
        bf16x8 a = *(const bf16x8*)(Aptr + kc * 32);
        size_t boff = (size_t)kc * 4096 + (size_t)lane * 8;
#pragma unroll
        for (int nt = 0; nt < 8; ++nt) {
            bf16x8 b0 = *(const bf16x8*)(Bq + boff + nt * 512);
            aq[nt] = __builtin_amdgcn_mfma_f32_16x16x32_bf16(a, b0, aq[nt], 0, 0, 0);
            bf16x8 b1 = *(const bf16x8*)(Bk + boff + nt * 512);
            ak[nt] = __builtin_amdgcn_mfma_f32_16x16x32_bf16(a, b1, ak[nt], 0, 0, 0);
            bf16x8 b2 = *(const bf16x8*)(Bv + boff + nt * 512);
            av[nt] = __builtin_amdgcn_mfma_f32_16x16x32_bf16(a, b2, av[nt], 0, 0, 0);
            bf16x8 b3 = *(const bf16x8*)(Bs + boff + nt * 512);
            as_[nt] = __builtin_amdgcn_mfma_f32_16x16x32_bf16(a, b3, as_[nt], 0, 0, 0);
        }
    }
    int col0 = lane & 15;
    int r0 = base + (lane >> 4) * 4;
#pragma unroll
    for (int nt = 0; nt < 8; ++nt) {
        int c = nt * 16 + col0;
        float bbq = bq[c], bbk = bk[c], bbv = bv[c], bbs = bs[c];
#pragma unroll
        for (int r = 0; r < 4; ++r) {
            int ro = r0 + r;
            if (ro < M) {
                qbf[(size_t)ro * 128 + c]        = f2bf(aq[nt][r] + bbq);
                kvbf[(size_t)ro * 256 + c]       = f2bf(ak[nt][r] + bbk);
                kvbf[(size_t)ro * 256 + 128 + c] = f2bf(av[nt][r] + bbv);
                xr[(size_t)ro * 128 + c]         = as_[nt][r] + bbs;
            }
        }
    }
}

// ---------- CSR build ----------
__global__ __launch_bounds__(256) void csr_hist(const int* __restrict__ ei,
                                                int* __restrict__ deg, int E) {
    int e = blockIdx.x * 256 + threadIdx.x;
    if (e < E) atomicAdd(&deg[ei[E + e]], 1);
}

__global__ __launch_bounds__(256) void scan_block_sums(const int* __restrict__ deg,
                                                       int* __restrict__ bsums, int N) {
    __shared__ int sd[256];
    int i = blockIdx.x * 256 + threadIdx.x;
    sd[threadIdx.x] = (i < N) ? deg[i] : 0;
    __syncthreads();
    for (int off = 128; off > 0; off >>= 1) {
        if (threadIdx.x < off) sd[threadIdx.x] += sd[threadIdx.x + off];
        __syncthreads();
    }
    if (threadIdx.x == 0) bsums[blockIdx.x] = sd[0];
}

__global__ __launch_bounds__(256) void scan_bsums(const int* __restrict__ bsums,
                                                  int* __restrict__ boff, int nb) {
    __shared__ int sd[256];
    int tid = threadIdx.x;
    int per = (nb + 255) / 256;
    int start = tid * per;
    int s = 0;
    for (int i = 0; i < per; ++i) {
        int idx = start + i;
        if (idx < nb) s += bsums[idx];
    }
    int my = s;
    sd[tid] = s;
    __syncthreads();
    for (int off = 1; off < 256; off <<= 1) {
        int t = (tid >= off) ? sd[tid - off] : 0;
        __syncthreads();
        sd[tid] += t;
        __syncthreads();
    }
    int run = sd[tid] - my;
    for (int i = 0; i < per; ++i) {
        int idx = start + i;
        if (idx < nb) {
            boff[idx] = run;
            run += bsums[idx];
        }
    }
}

__global__ __launch_bounds__(256) void scan_local(const int* __restrict__ deg,
                                                  const int* __restrict__ boff,
                                                  int* __restrict__ rowptr,
                                                  int* __restrict__ wrptr, int N, int E) {
    __shared__ int sd[256];
    int i = blockIdx.x * 256 + threadIdx.x;
    int v = (i < N) ? deg[i] : 0;
    sd[threadIdx.x] = v;
    __syncthreads();
    for (int off = 1; off < 256; off <<= 1) {
        int t = (threadIdx.x >= off) ? sd[threadIdx.x - off] : 0;
        __syncthreads();
        sd[threadIdx.x] += t;
        __syncthreads();
    }
    if (i < N) {
        int excl = sd[threadIdx.x] - v + boff[blockIdx.x];
        rowptr[i] = excl;
        wrptr[i] = excl;
        if (i == N - 1) rowptr[N] = E;
    }
}

__global__ __launch_bounds__(256) void csr_fill(const int* __restrict__ ei,
                                                const float* __restrict__ ea,
                                                int* __restrict__ wrptr,
                                                int* __restrict__ csr_src,
                                                float* __restrict__ csr_w, int E) {
    int e = blockIdx.x * 256 + threadIdx.x;
    if (e >= E) return;
    int tgt = ei[E + e];
    int pos = atomicAdd(&wrptr[tgt], 1);
    csr_src[pos] = ei[e];
    csr_w[pos] = ea[e];
}

// ---------- attention gather v4: 16 lanes/node + fused BN stats ----------
// BN channel sums computed in-registers, reduced via shuffle (cross node-group),
// LDS (cross-wave), then atomicAdd into 8 strided replicas (~390 adds/address).
__global__ __launch_bounds__(256) void attn_gather(const unsigned short* __restrict__ qbf,
                                                   const unsigned short* __restrict__ kvbf,
                                                   const float* __restrict__ xr,
                                                   const int* __restrict__ rowptr,
                                                   const int* __restrict__ csr_src,
                                                   const float* __restrict__ csr_w,
                                                   const float* __restrict__ Wel,
                                                   const float* __restrict__ Wb,
                                                   float* __restrict__ out,
                                                   float* __restrict__ bsumR,
                                                   float* __restrict__ bsumsqR, int N) {
    __shared__ float sdS[4][128];
    __shared__ float sdQ[4][128];
    int tid = threadIdx.x;
    int n = blockIdx.x * 16 + (tid >> 4);
    int sl = tid & 15;
    int wave = tid >> 6, lane = tid & 63;
    bool live = (n < N);
    int nn = live ? n : (N - 1);

    uint4 qu = ((const uint4*)(qbf + (size_t)nn * 128))[sl];
    float qf[8];
    bfu2(qu.x, qf[0], qf[1]); bfu2(qu.y, qf[2], qf[3]);
    bfu2(qu.z, qf[4], qf[5]); bfu2(qu.w, qf[6], qf[7]);
    float wef[8];
    {
        float4 w0 = ((const float4*)Wel)[sl * 2];
        float4 w1 = ((const float4*)Wel)[sl * 2 + 1];
        wef[0] = w0.x; wef[1] = w0.y; wef[2] = w0.z; wef[3] = w0.w;
        wef[4] = w1.x; wef[5] = w1.y; wef[6] = w1.z; wef[7] = w1.w;
    }
    float qwe = 0.f;
#pragma unroll
    for (int c = 0; c < 8; ++c) qwe += qf[c] * wef[c];
    qwe += __shfl_xor(qwe, 1);
    qwe += __shfl_xor(qwe, 2);

    float l = 0.f;
    float acc[8];
#pragma unroll
    for (int c = 0; c < 8; ++c) acc[c] = 0.f;

    int beg = live ? rowptr[nn] : 0;
    int end = live ? rowptr[nn + 1] : 0;
    int i = beg;
    if (i < end) {
        float w = csr_w[i];
        const uint4* kvr = (const uint4*)(kvbf + (size_t)csr_src[i] * 256);
        uint4 ku = kvr[sl];
        uint4 vu = kvr[16 + sl];
        for (;;) {
            float wc = w;
            uint4 kuc = ku, vuc = vu;
            ++i;
            bool more = (i < end);
            if (more) {
                float w2 = csr_w[i];
                const uint4* kvr2 = (const uint4*)(kvbf + (size_t)csr_src[i] * 256);
                ku = kvr2[sl];
                vu = kvr2[16 + sl];
                w = w2;
            }
            float kf[8];
            bfu2(kuc.x, kf[0], kf[1]); bfu2(kuc.y, kf[2], kf[3]);
            bfu2(kuc.z, kf[4], kf[5]); bfu2(kuc.w, kf[6], kf[7]);
            float d = 0.f;
#pragma unroll
            for (int c = 0; c < 8; ++c) d += qf[c] * kf[c];
            d += __shfl_xor(d, 1);
            d += __shfl_xor(d, 2);
            float p = __expf((d + wc * qwe) * 0.17677669529663687f);
            l += p;
            float vf[8];
            bfu2(vuc.x, vf[0], vf[1]); bfu2(vuc.y, vf[2], vf[3]);
            bfu2(vuc.z, vf[4], vf[5]); bfu2(vuc.w, vf[6], vf[7]);
#pragma unroll
            for (int c = 0; c < 8; ++c)
                acc[c] += p * (vf[c] + wc * wef[c]);
            if (!more) break;
        }
    }

    float inv = (l > 0.f) ? 1.f / l : 0.f;
    float ox[8];
#pragma unroll
    for (int c = 0; c < 8; ++c) ox[c] = acc[c] * inv;

    const float* xrow = xr + (size_t)nn * 128;
    float4 a0 = ((const float4*)xrow)[sl * 2];
    float4 a1 = ((const float4*)xrow)[sl * 2 + 1];
    float xv[8] = {a0.x, a0.y, a0.z, a0.w, a1.x, a1.y, a1.z, a1.w};
    float4 b0 = ((const float4*)Wb)[sl * 2];
    float4 b1 = ((const float4*)Wb)[sl * 2 + 1];
    float4 c0 = ((const float4*)(Wb + 128))[sl * 2];
    float4 c1 = ((const float4*)(Wb + 128))[sl * 2 + 1];
    float4 d0 = ((const float4*)(Wb + 256))[sl * 2];
    float4 d1 = ((const float4*)(Wb + 256))[sl * 2 + 1];
    float wb0[8] = {b0.x, b0.y, b0.z, b0.w, b1.x, b1.y, b1.z, b1.w};
    float wb1[8] = {c0.x, c0.y, c0.z, c0.w, c1.x, c1.y, c1.z, c1.w};
    float wb2[8] = {d0.x, d0.y, d0.z, d0.w, d1.x, d1.y, d1.z, d1.w};
    float part = 0.f;
#pragma unroll
    for (int c = 0; c < 8; ++c)
        part += ox[c] * wb0[c] + xv[c] * wb1[c] + (ox[c] - xv[c]) * wb2[c];
    part += __shfl_xor(part, 1); part += __shfl_xor(part, 2);
    part += __shfl_xor(part, 4); part += __shfl_xor(part, 8);
    float beta = 1.f / (1.f + __expf(-part));

    float r[8];
#pragma unroll
    for (int c = 0; c < 8; ++c)
        r[c] = beta * xv[c] + (1.f - beta) * ox[c];

    if (live) {
        ((float4*)(out + (size_t)n * 128))[sl * 2] =
            make_float4(r[0], r[1], r[2], r[3]);
        ((float4*)(out + (size_t)n * 128))[sl * 2 + 1] =
            make_float4(r[4], r[5], r[6], r[7]);
    }

    // ---- fused BN stats ----
    float s8[8], q8[8];
#pragma unroll
    for (int c = 0; c < 8; ++c) {
        s8[c] = live ? r[c] : 0.f;
        q8[c] = live ? r[c] * r[c] : 0.f;
    }
#pragma unroll
    for (int c = 0; c < 8; ++c) {
        s8[c] += __shfl_xor(s8[c], 16); s8[c] += __shfl_xor(s8[c], 32);
        q8[c] += __shfl_xor(q8[c], 16); q8[c] += __shfl_xor(q8[c], 32);
    }
    if ((lane >> 4) == 0) {
#pragma unroll
        for (int c = 0; c < 8; ++c) {
            sdS[wave][sl * 8 + c] = s8[c];
            sdQ[wave][sl * 8 + c] = q8[c];
        }
    }
    __syncthreads();
    if (tid < 128) {
        float s = sdS[0][tid] + sdS[1][tid] + sdS[2][tid] + sdS[3][tid];
        float q = sdQ[0][tid] + sdQ[1][tid] + sdQ[2][tid] + sdQ[3][tid];
        int rep = blockIdx.x & 7;
        atomicAdd(&bsumR[rep * 128 + tid], s);
        atomicAdd(&bsumsqR[rep * 128 + tid], q);
    }
}

// ---------- BN apply + ReLU + residual (+ optional bf16 side-write), 8-replica stats ----------
__global__ __launch_bounds__(256) void bn_apply(const float* __restrict__ o,
                                                const float* __restrict__ hres,
                                                float* __restrict__ hout,
                                                unsigned short* __restrict__ hout_bf,
                                                const float* __restrict__ bsumR,
                                                const float* __restrict__ bsumsqR,
                                                const float* __restrict__ gamma,
                                                const float* __restrict__ bbeta,
                                                int N, float invN) {
    int i = blockIdx.x * 256 + threadIdx.x;
    if (i >= N * 32) return;
    int c4 = i & 31;
    float4 s = make_float4(0.f, 0.f, 0.f, 0.f), ss = s;
#pragma unroll
    for (int rep = 0; rep < 8; ++rep) {
        float4 sv = ((const float4*)bsumR)[rep * 32 + c4];
        float4 qv = ((const float4*)bsumsqR)[rep * 32 + c4];
        s.x += sv.x; s.y += sv.y; s.z += sv.z; s.w += sv.w;
        ss.x += qv.x; ss.y += qv.y; ss.z += qv.z; ss.w += qv.w;
    }
    float4 g = ((const float4*)gamma)[c4];
    float4 b = ((const float4*)bbeta)[c4];
    float4 ov = ((const float4*)o)[i];
    float4 hr = ((const float4*)hres)[i];
    float4 r;
    { float mu = s.x * invN, var = ss.x * invN - mu * mu;
      r.x = fmaxf((ov.x - mu) * (g.x * rsqrtf(var + EPS)) + b.x, 0.f) + hr.x; }
    { float mu = s.y * invN, var = ss.y * invN - mu * mu;
      r.y = fmaxf((ov.y - mu) * (g.y * rsqrtf(var + EPS)) + b.y, 0.f) + hr.y; }
    { float mu = s.z * invN, var = ss.z * invN - mu * mu;
      r.z = fmaxf((ov.z - mu) * (g.z * rsqrtf(var + EPS)) + b.z, 0.f) + hr.z; }
    { float mu = s.w * invN, var = ss.w * invN - mu * mu;
      r.w = fmaxf((ov.w - mu) * (g.w * rsqrtf(var + EPS)) + b.w, 0.f) + hr.w; }
    ((float4*)hout)[i] = r;
    if (hout_bf) {
        ushort4 ob = make_ushort4(f2bf(r.x), f2bf(r.y), f2bf(r.z), f2bf(r.w));
        ((ushort4*)hout_bf)[i] = ob;
    }
}

extern "C" void kernel_launch(void* const* d_in, const int* in_sizes, int n_in,
                              void* d_out, int out_size, void* d_ws, size_t ws_size,
                              hipStream_t stream) {
    const float* x     = (const float*)d_in[0];
    const int*   ei    = (const int*)d_in[1];
    const float* ea    = (const float*)d_in[2];
    const float* W_in  = (const float*)d_in[3];
    const float* b_in  = (const float*)d_in[4];
    const float* Wq    = (const float*)d_in[5];
    const float* bq    = (const float*)d_in[6];
    const float* Wk    = (const float*)d_in[7];
    const float* bk    = (const float*)d_in[8];
    const float* Wv    = (const float*)d_in[9];
    const float* bv    = (const float*)d_in[10];
    const float* We    = (const float*)d_in[11];
    const float* Wskip = (const float*)d_in[12];
    const float* bskip = (const float*)d_in[13];
    const float* Wbeta = (const float*)d_in[14];
    const float* bn_g  = (const float*)d_in[15];
    const float* bn_b  = (const float*)d_in[16];

    const int N = in_sizes[0] / 128;
    const int E = in_sizes[1] / 2;

    float* ws = (float*)d_ws;
    unsigned short* Bpack = (unsigned short*)ws;           // 9*16384 bf16 = 73728 floats
    size_t off = 73728;
    unsigned short* xbf  = (unsigned short*)(ws + off);               off += (size_t)N * 64;
    unsigned short* hbf  = (unsigned short*)(ws + off);               off += (size_t)N * 64;
    unsigned short* qbf  = (unsigned short*)(ws + off);               off += (size_t)N * 64;
    unsigned short* kvbf = (unsigned short*)(ws + off);               off += (size_t)N * 128;
    float* h    = ws + off;  off += (size_t)N * 128;
    float* xr   = ws + off;  off += (size_t)N * 128;
    float* attn = ws + off;  off += (size_t)N * 128;
    float* bsumR   = ws + off;  off += 1024;               // 8 replicas x 128
    float* bsumsqR = ws + off;  off += 1024;
    float* csr_w   = ws + off;  off += (size_t)E;
    int* deg     = (int*)(ws + off);
    int* rowptr  = deg + N;
    int* wrptr   = rowptr + (N + 1);
    int* csr_src = wrptr + N;
    int* bsums   = csr_src + E;
    int* boff    = bsums + ((N + 255) / 256 + 1);

    dim3 blk(256);
    int gGemm   = (N + 63) / 64;
    int gNode16 = (N + 15) / 16;
    int gEdge   = (E + 255) / 256;
    int gApply  = (N * 32 + 255) / 256;
    int nbScan  = (N + 255) / 256;

    // ---- weight pack + x convert ----
    pack_w9<<<(9 * 16384 + 255) / 256, blk, 0, stream>>>(
        W_in, Wq, Wk, Wv, Wskip, Wq + 16384, Wk + 16384, Wv + 16384, Wskip + 16384, Bpack);
    f32_to_bf16<<<gApply, blk, 0, stream>>>(x, xbf, N * 32);

    // ---- CSR build ----
    hipMemsetAsync(deg, 0, (size_t)N * sizeof(int), stream);
    csr_hist<<<gEdge, blk, 0, stream>>>(ei, deg, E);
    scan_block_sums<<<nbScan, blk, 0, stream>>>(deg, bsums, N);
    scan_bsums<<<1, blk, 0, stream>>>(bsums, boff, nbScan);
    scan_local<<<nbScan, blk, 0, stream>>>(deg, boff, rowptr, wrptr, N, E);
    csr_fill<<<gEdge, blk, 0, stream>>>(ei, ea, wrptr, csr_src, csr_w, E);

    // ---- input projection (writes h fp32 + hbf bf16) ----
    gemm_mfma<1, 1><<<gGemm, blk, 0, stream>>>(xbf, Bpack + 0 * 16384, b_in, h, hbf, N);

    for (int l = 0; l < 2; ++l) {
        const unsigned short* Bq = Bpack + (size_t)(1 + l * 4 + 0) * 16384;
        const unsigned short* Bk = Bpack + (size_t)(1 + l * 4 + 1) * 16384;
        const unsigned short* Bv = Bpack + (size_t)(1 + l * 4 + 2) * 16384;
        const unsigned short* Bs = Bpack + (size_t)(1 + l * 4 + 3) * 16384;
        gemm_qkvs<<<gGemm, blk, 0, stream>>>(hbf, Bq, Bk, Bv, Bs,
                                             bq + l * 128, bk + l * 128, bv + l * 128, bskip + l * 128,
                                             qbf, kvbf, xr, N);
        hipMemsetAsync(bsumR, 0, 2048 * sizeof(float), stream);
        attn_gather<<<gNode16, blk, 0, stream>>>(qbf, kvbf, xr, rowptr, csr_src, csr_w,
                                                 We + l * 128, Wbeta + l * 384, attn,
                                                 bsumR, bsumsqR, N);
        bn_apply<<<gApply, blk, 0, stream>>>(attn, h, (l == 1) ? (float*)d_out : h,
                                             (l == 0) ? hbf : (unsigned short*)0,
                                             bsumR, bsumsqR, bn_g + l * 128, bn_b + l * 128,
                                             N, 1.0f / (float)N);
    }
}

// Round 12
// 346.204 us; speedup vs baseline: 1.4771x; 1.0462x over previous
//
#include <hip/hip_runtime.h>
#include <hip/hip_bf16.h>
#include <math.h>

#define EPS 1e-5f

typedef __attribute__((ext_vector_type(8))) short bf16x8;
typedef __attribute__((ext_vector_type(4))) float f32x4;

__device__ __forceinline__ unsigned short f2bf(float f) {
    unsigned u = __float_as_uint(f);
    unsigned r = (u + 0x7FFFu + ((u >> 16) & 1u)) >> 16;   // RNE
    return (unsigned short)r;
}
__device__ __forceinline__ unsigned f2bf2(float lo, float hi) {
    return (unsigned)f2bf(lo) | ((unsigned)f2bf(hi) << 16);
}
__device__ __forceinline__ float bf2f(unsigned short u) {
    return __uint_as_float((unsigned)u << 16);
}
__device__ __forceinline__ void bfu2(unsigned u, float& lo, float& hi) {
    lo = __uint_as_float(u << 16);
    hi = __uint_as_float(u & 0xFFFF0000u);
}

// ---------- weight pack: 9 matrices fp32 [128k x 128n] -> bf16 B-fragment order ----------
// Column-tiling chosen so fragment (nt,col0) = W column col0*8+nt: a lane's 8
// nt-accumulators are then 8 CONSECUTIVE output channels -> 16B coalesced
// epilogue stores, with buffers staying plain row-major (identity permutation).
__global__ __launch_bounds__(256) void pack_w9(const float* __restrict__ W0, const float* __restrict__ W1,
                                               const float* __restrict__ W2, const float* __restrict__ W3,
                                               const float* __restrict__ W4, const float* __restrict__ W5,
                                               const float* __restrict__ W6, const float* __restrict__ W7,
                                               const float* __restrict__ W8, unsigned short* __restrict__ out) {
    int t = blockIdx.x * 256 + threadIdx.x;
    if (t >= 9 * 16384) return;
    int mat = t >> 14, r = t & 16383;
    const float* W;
    switch (mat) {
        case 0: W = W0; break; case 1: W = W1; break; case 2: W = W2; break;
        case 3: W = W3; break; case 4: W = W4; break; case 5: W = W5; break;
        case 6: W = W6; break; case 7: W = W7; break; default: W = W8; break;
    }
    int j = r & 7, lane = (r >> 3) & 63, nt = (r >> 9) & 7, kc = r >> 12;
    int k = kc * 32 + (lane >> 4) * 8 + j;
    int n = (lane & 15) * 8 + nt;            // was nt*16+(lane&15)
    out[t] = f2bf(W[k * 128 + n]);
}

// ---------- fp32 -> bf16 elementwise ----------
__global__ __launch_bounds__(256) void f32_to_bf16(const float* __restrict__ in,
                                                   unsigned short* __restrict__ out, int n4) {
    int i = blockIdx.x * 256 + threadIdx.x;
    if (i >= n4) return;
    float4 v = ((const float4*)in)[i];
    ushort4 o = make_ushort4(f2bf(v.x), f2bf(v.y), f2bf(v.z), f2bf(v.w));
    ((ushort4*)out)[i] = o;
}

// ---------- MFMA GEMM, coalesced epilogue (channels col0*8..col0*8+7 per lane) ----------
template <int ACT, int WBF>
__global__ __launch_bounds__(256) void gemm_mfma(const unsigned short* __restrict__ Abf,
                                                 const unsigned short* __restrict__ Bp,
                                                 const float* __restrict__ bias,
                                                 float* __restrict__ C,
                                                 unsigned short* __restrict__ Cbf, int M) {
    int wave = threadIdx.x >> 6, lane = threadIdx.x & 63;
    int base = blockIdx.x * 64 + wave * 16;
    int m = lane & 15, kg = lane >> 4;
    int arow = base + m; if (arow >= M) arow = M - 1;
    const unsigned short* Aptr = Abf + (size_t)arow * 128 + kg * 8;
    f32x4 acc[8];
#pragma unroll
    for (int nt = 0; nt < 8; ++nt) acc[nt] = (f32x4)(0.f);
#pragma unroll
    for (int kc = 0; kc < 4; ++kc) {
        bf16x8 a = *(const bf16x8*)(Aptr + kc * 32);
        const unsigned short* bp = Bp + (size_t)kc * 4096 + (size_t)lane * 8;
#pragma unroll
        for (int nt = 0; nt < 8; ++nt) {
            bf16x8 b = *(const bf16x8*)(bp + nt * 512);
            acc[nt] = __builtin_amdgcn_mfma_f32_16x16x32_bf16(a, b, acc[nt], 0, 0, 0);
        }
    }
    int col0 = lane & 15;
    int r0 = base + (lane >> 4) * 4;
    float4 bl = *(const float4*)&bias[col0 * 8];
    float4 bh = *(const float4*)&bias[col0 * 8 + 4];
#pragma unroll
    for (int r = 0; r < 4; ++r) {
        int ro = r0 + r;
        if (ro < M) {
            float v0 = acc[0][r] + bl.x, v1 = acc[1][r] + bl.y;
            float v2 = acc[2][r] + bl.z, v3 = acc[3][r] + bl.w;
            float v4 = acc[4][r] + bh.x, v5 = acc[5][r] + bh.y;
            float v6 = acc[6][r] + bh.z, v7 = acc[7][r] + bh.w;
            if (ACT) {
                v0 = fmaxf(v0, 0.f); v1 = fmaxf(v1, 0.f); v2 = fmaxf(v2, 0.f); v3 = fmaxf(v3, 0.f);
                v4 = fmaxf(v4, 0.f); v5 = fmaxf(v5, 0.f); v6 = fmaxf(v6, 0.f); v7 = fmaxf(v7, 0.f);
            }
            size_t o = (size_t)ro * 128 + col0 * 8;
            *(float4*)&C[o]     = make_float4(v0, v1, v2, v3);
            *(float4*)&C[o + 4] = make_float4(v4, v5, v6, v7);
            if (WBF)
                *(uint4*)&Cbf[o] = make_uint4(f2bf2(v0, v1), f2bf2(v2, v3),
                                              f2bf2(v4, v5), f2bf2(v6, v7));
        }
    }
}

// ---------- fused 4-output MFMA GEMM, coalesced epilogue ----------
__global__ __launch_bounds__(256) void gemm_qkvs(const unsigned short* __restrict__ Abf,
                                                 const unsigned short* __restrict__ Bq,
                                                 const unsigned short* __restrict__ Bk,
                                                 const unsigned short* __restrict__ Bv,
                                                 const unsigned short* __restrict__ Bs,
                                                 const float* __restrict__ bq,
                                                 const float* __restrict__ bk,
                                                 const float* __restrict__ bv,
                                                 const float* __restrict__ bs,
                                                 unsigned short* __restrict__ qbf,
                                                 unsigned short* __restrict__ kvbf,
                                                 float* __restrict__ xr, int M) {
    int wave = threadIdx.x >> 6, lane = threadIdx.x & 63;
    int base = blockIdx.x * 64 + wave * 16;
    int m = lane & 15, kg = lane >> 4;
    int arow = base + m; if (arow >= M) arow = M - 1;
    const unsigned short* Aptr = Abf + (size_t)arow * 128 + kg * 8;
    f32x4 aq[8], ak[8], av[8], as_[8];
#pragma unroll
    for (int nt = 0; nt < 8; ++nt) { aq[nt] = (f32x4)(0.f); ak[nt] = (f32x4)(0.f);
                                     av[nt] = (f32x4)(0.f); as_[nt] = (f32x4)(0.f); }
#pragma unroll
    for (int kc = 0; kc < 4; ++kc) {
        bf16x8 a = *(const bf16x8*)(Aptr + kc * 32);
        size_t boff = (size_t)kc * 4096 + (size_t)lane * 8;
#pragma unroll
        for (int nt = 0; nt < 8; ++nt) {
            bf16x8 b0 = *(const bf16x8*)(Bq + boff + nt * 512);
            aq[nt] = __builtin_amdgcn_mfma_f32_16x16x32_bf16(a, b0, aq[nt], 0, 0, 0);
            bf16x8 b1 = *(const bf16x8*)(Bk + boff + nt * 512);
            ak[nt] = __builtin_amdgcn_mfma_f32_16x16x32_bf16(a, b1, ak[nt], 0, 0, 0);
            bf16x8 b2 = *(const bf16x8*)(Bv + boff + nt * 512);
            av[nt] = __builtin_amdgcn_mfma_f32_16x16x32_bf16(a, b2, av[nt], 0, 0, 0);
            bf16x8 b3 = *(const bf16x8*)(Bs + boff + nt * 512);
            as_[nt] = __builtin_amdgcn_mfma_f32_16x16x32_bf16(a, b3, as_[nt], 0, 0, 0);
        }
    }
    int col0 = lane & 15;
    int r0 = base + (lane >> 4) * 4;
    float4 bql = *(const float4*)&bq[col0 * 8], bqh = *(const float4*)&bq[col0 * 8 + 4];
    float4 bkl = *(const float4*)&bk[col0 * 8], bkh = *(const float4*)&bk[col0 * 8 + 4];
    float4 bvl = *(const float4*)&bv[col0 * 8], bvh = *(const float4*)&bv[col0 * 8 + 4];
    float4 bsl = *(const float4*)&bs[col0 * 8], bsh = *(const float4*)&bs[col0 * 8 + 4];
#pragma unroll
    for (int r = 0; r < 4; ++r) {
        int ro = r0 + r;
        if (ro < M) {
            size_t qo = (size_t)ro * 128 + col0 * 8;
            size_t kvo = (size_t)ro * 256 + col0 * 8;
            *(uint4*)&qbf[qo] = make_uint4(
                f2bf2(aq[0][r] + bql.x, aq[1][r] + bql.y), f2bf2(aq[2][r] + bql.z, aq[3][r] + bql.w),
                f2bf2(aq[4][r] + bqh.x, aq[5][r] + bqh.y), f2bf2(aq[6][r] + bqh.z, aq[7][r] + bqh.w));
            *(uint4*)&kvbf[kvo] = make_uint4(
                f2bf2(ak[0][r] + bkl.x, ak[1][r] + bkl.y), f2bf2(ak[2][r] + bkl.z, ak[3][r] + bkl.w),
                f2bf2(ak[4][r] + bkh.x, ak[5][r] + bkh.y), f2bf2(ak[6][r] + bkh.z, ak[7][r] + bkh.w));
            *(uint4*)&kvbf[kvo + 128] = make_uint4(
                f2bf2(av[0][r] + bvl.x, av[1][r] + bvl.y), f2bf2(av[2][r] + bvl.z, av[3][r] + bvl.w),
                f2bf2(av[4][r] + bvh.x, av[5][r] + bvh.y), f2bf2(av[6][r] + bvh.z, av[7][r] + bvh.w));
            *(float4*)&xr[qo]     = make_float4(as_[0][r] + bsl.x, as_[1][r] + bsl.y,
                                                as_[2][r] + bsl.z, as_[3][r] + bsl.w);
            *(float4*)&xr[qo + 4] = make_float4(as_[4][r] + bsh.x, as_[5][r] + bsh.y,
                                                as_[6][r] + bsh.z, as_[7][r] + bsh.w);
        }
    }
}

// ---------- CSR build ----------
__global__ __launch_bounds__(256) void csr_hist(const int* __restrict__ ei,
                                                int* __restrict__ deg, int E) {
    int e = blockIdx.x * 256 + threadIdx.x;
    if (e < E) atomicAdd(&deg[ei[E + e]], 1);
}

__global__ __launch_bounds__(256) void scan_block_sums(const int* __restrict__ deg,
                                                       int* __restrict__ bsums, int N) {
    __shared__ int sd[256];
    int i = blockIdx.x * 256 + threadIdx.x;
    sd[threadIdx.x] = (i < N) ? deg[i] : 0;
    __syncthreads();
    for (int off = 128; off > 0; off >>= 1) {
        if (threadIdx.x < off) sd[threadIdx.x] += sd[threadIdx.x + off];
        __syncthreads();
    }
    if (threadIdx.x == 0) bsums[blockIdx.x] = sd[0];
}

__global__ __launch_bounds__(256) void scan_bsums(const int* __restrict__ bsums,
                                                  int* __restrict__ boff, int nb) {
    __shared__ int sd[256];
    int tid = threadIdx.x;
    int per = (nb + 255) / 256;
    int start = tid * per;
    int s = 0;
    for (int i = 0; i < per; ++i) {
        int idx = start + i;
        if (idx < nb) s += bsums[idx];
    }
    int my = s;
    sd[tid] = s;
    __syncthreads();
    for (int off = 1; off < 256; off <<= 1) {
        int t = (tid >= off) ? sd[tid - off] : 0;
        __syncthreads();
        sd[tid] += t;
        __syncthreads();
    }
    int run = sd[tid] - my;
    for (int i = 0; i < per; ++i) {
        int idx = start + i;
        if (idx < nb) {
            boff[idx] = run;
            run += bsums[idx];
        }
    }
}

__global__ __launch_bounds__(256) void scan_local(const int* __restrict__ deg,
                                                  const int* __restrict__ boff,
                                                  int* __restrict__ rowptr,
                                                  int* __restrict__ wrptr, int N, int E) {
    __shared__ int sd[256];
    int i = blockIdx.x * 256 + threadIdx.x;
    int v = (i < N) ? deg[i] : 0;
    sd[threadIdx.x] = v;
    __syncthreads();
    for (int off = 1; off < 256; off <<= 1) {
        int t = (threadIdx.x >= off) ? sd[threadIdx.x - off] : 0;
        __syncthreads();
        sd[threadIdx.x] += t;
        __syncthreads();
    }
    if (i < N) {
        int excl = sd[threadIdx.x] - v + boff[blockIdx.x];
        rowptr[i] = excl;
        wrptr[i] = excl;
        if (i == N - 1) rowptr[N] = E;
    }
}

__global__ __launch_bounds__(256) void csr_fill(const int* __restrict__ ei,
                                                const float* __restrict__ ea,
                                                int* __restrict__ wrptr,
                                                int* __restrict__ csr_src,
                                                float* __restrict__ csr_w, int E) {
    int e = blockIdx.x * 256 + threadIdx.x;
    if (e >= E) return;
    int tgt = ei[E + e];
    int pos = atomicAdd(&wrptr[tgt], 1);
    csr_src[pos] = ei[e];
    csr_w[pos] = ea[e];
}

// ---------- attention gather v4: 16 lanes/node + fused BN stats ----------
__global__ __launch_bounds__(256) void attn_gather(const unsigned short* __restrict__ qbf,
                                                   const unsigned short* __restrict__ kvbf,
                                                   const float* __restrict__ xr,
                                                   const int* __restrict__ rowptr,
                                                   const int* __restrict__ csr_src,
                                                   const float* __restrict__ csr_w,
                                                   const float* __restrict__ Wel,
                                                   const float* __restrict__ Wb,
                                                   float* __restrict__ out,
                                                   float* __restrict__ bsumR,
                                                   float* __restrict__ bsumsqR, int N) {
    __shared__ float sdS[4][128];
    __shared__ float sdQ[4][128];
    int tid = threadIdx.x;
    int n = blockIdx.x * 16 + (tid >> 4);
    int sl = tid & 15;
    int wave = tid >> 6, lane = tid & 63;
    bool live = (n < N);
    int nn = live ? n : (N - 1);

    uint4 qu = ((const uint4*)(qbf + (size_t)nn * 128))[sl];
    float qf[8];
    bfu2(qu.x, qf[0], qf[1]); bfu2(qu.y, qf[2], qf[3]);
    bfu2(qu.z, qf[4], qf[5]); bfu2(qu.w, qf[6], qf[7]);
    float wef[8];
    {
        float4 w0 = ((const float4*)Wel)[sl * 2];
        float4 w1 = ((const float4*)Wel)[sl * 2 + 1];
        wef[0] = w0.x; wef[1] = w0.y; wef[2] = w0.z; wef[3] = w0.w;
        wef[4] = w1.x; wef[5] = w1.y; wef[6] = w1.z; wef[7] = w1.w;
    }
    float qwe = 0.f;
#pragma unroll
    for (int c = 0; c < 8; ++c) qwe += qf[c] * wef[c];
    qwe += __shfl_xor(qwe, 1);
    qwe += __shfl_xor(qwe, 2);

    float l = 0.f;
    float acc[8];
#pragma unroll
    for (int c = 0; c < 8; ++c) acc[c] = 0.f;

    int beg = live ? rowptr[nn] : 0;
    int end = live ? rowptr[nn + 1] : 0;
    int i = beg;
    if (i < end) {
        float w = csr_w[i];
        const uint4* kvr = (const uint4*)(kvbf + (size_t)csr_src[i] * 256);
        uint4 ku = kvr[sl];
        uint4 vu = kvr[16 + sl];
        for (;;) {
            float wc = w;
            uint4 kuc = ku, vuc = vu;
            ++i;
            bool more = (i < end);
            if (more) {
                float w2 = csr_w[i];
                const uint4* kvr2 = (const uint4*)(kvbf + (size_t)csr_src[i] * 256);
                ku = kvr2[sl];
                vu = kvr2[16 + sl];
                w = w2;
            }
            float kf[8];
            bfu2(kuc.x, kf[0], kf[1]); bfu2(kuc.y, kf[2], kf[3]);
            bfu2(kuc.z, kf[4], kf[5]); bfu2(kuc.w, kf[6], kf[7]);
            float d = 0.f;
#pragma unroll
            for (int c = 0; c < 8; ++c) d += qf[c] * kf[c];
            d += __shfl_xor(d, 1);
            d += __shfl_xor(d, 2);
            float p = __expf((d + wc * qwe) * 0.17677669529663687f);
            l += p;
            float vf[8];
            bfu2(vuc.x, vf[0], vf[1]); bfu2(vuc.y, vf[2], vf[3]);
            bfu2(vuc.z, vf[4], vf[5]); bfu2(vuc.w, vf[6], vf[7]);
#pragma unroll
            for (int c = 0; c < 8; ++c)
                acc[c] += p * (vf[c] + wc * wef[c]);
            if (!more) break;
        }
    }

    float inv = (l > 0.f) ? 1.f / l : 0.f;
    float ox[8];
#pragma unroll
    for (int c = 0; c < 8; ++c) ox[c] = acc[c] * inv;

    const float* xrow = xr + (size_t)nn * 128;
    float4 a0 = ((const float4*)xrow)[sl * 2];
    float4 a1 = ((const float4*)xrow)[sl * 2 + 1];
    float xv[8] = {a0.x, a0.y, a0.z, a0.w, a1.x, a1.y, a1.z, a1.w};
    float4 b0 = ((const float4*)Wb)[sl * 2];
    float4 b1 = ((const float4*)Wb)[sl * 2 + 1];
    float4 c0 = ((const float4*)(Wb + 128))[sl * 2];
    float4 c1 = ((const float4*)(Wb + 128))[sl * 2 + 1];
    float4 d0 = ((const float4*)(Wb + 256))[sl * 2];
    float4 d1 = ((const float4*)(Wb + 256))[sl * 2 + 1];
    float wb0[8] = {b0.x, b0.y, b0.z, b0.w, b1.x, b1.y, b1.z, b1.w};
    float wb1[8] = {c0.x, c0.y, c0.z, c0.w, c1.x, c1.y, c1.z, c1.w};
    float wb2[8] = {d0.x, d0.y, d0.z, d0.w, d1.x, d1.y, d1.z, d1.w};
    float part = 0.f;
#pragma unroll
    for (int c = 0; c < 8; ++c)
        part += ox[c] * wb0[c] + xv[c] * wb1[c] + (ox[c] - xv[c]) * wb2[c];
    part += __shfl_xor(part, 1); part += __shfl_xor(part, 2);
    part += __shfl_xor(part, 4); part += __shfl_xor(part, 8);
    float beta = 1.f / (1.f + __expf(-part));

    float r[8];
#pragma unroll
    for (int c = 0; c < 8; ++c)
        r[c] = beta * xv[c] + (1.f - beta) * ox[c];

    if (live) {
        ((float4*)(out + (size_t)n * 128))[sl * 2] =
            make_float4(r[0], r[1], r[2], r[3]);
        ((float4*)(out + (size_t)n * 128))[sl * 2 + 1] =
            make_float4(r[4], r[5], r[6], r[7]);
    }

    // ---- fused BN stats ----
    float s8[8], q8[8];
#pragma unroll
    for (int c = 0; c < 8; ++c) {
        s8[c] = live ? r[c] : 0.f;
        q8[c] = live ? r[c] * r[c] : 0.f;
    }
#pragma unroll
    for (int c = 0; c < 8; ++c) {
        s8[c] += __shfl_xor(s8[c], 16); s8[c] += __shfl_xor(s8[c], 32);
        q8[c] += __shfl_xor(q8[c], 16); q8[c] += __shfl_xor(q8[c], 32);
    }
    if ((lane >> 4) == 0) {
#pragma unroll
        for (int c = 0; c < 8; ++c) {
            sdS[wave][sl * 8 + c] = s8[c];
            sdQ[wave][sl * 8 + c] = q8[c];
        }
    }
    __syncthreads();
    if (tid < 128) {
        float s = sdS[0][tid] + sdS[1][tid] + sdS[2][tid] + sdS[3][tid];
        float q = sdQ[0][tid] + sdQ[1][tid] + sdQ[2][tid] + sdQ[3][tid];
        int rep = blockIdx.x & 7;
        atomicAdd(&bsumR[rep * 128 + tid], s);
        atomicAdd(&bsumsqR[rep * 128 + tid], q);
    }
}

// ---------- BN apply + ReLU + residual (+ optional bf16 side-write), 8-replica stats ----------
__global__ __launch_bounds__(256) void bn_apply(const float* __restrict__ o,
                                                const float* __restrict__ hres,
                                                float* __restrict__ hout,
                                                unsigned short* __restrict__ hout_bf,
                                                const float* __restrict__ bsumR,
                                                const float* __restrict__ bsumsqR,
                                                const float* __restrict__ gamma,
                                                const float* __restrict__ bbeta,
                                                int N, float invN) {
    int i = blockIdx.x * 256 + threadIdx.x;
    if (i >= N * 32) return;
    int c4 = i & 31;
    float4 s = make_float4(0.f, 0.f, 0.f, 0.f), ss = s;
#pragma unroll
    for (int rep = 0; rep < 8; ++rep) {
        float4 sv = ((const float4*)bsumR)[rep * 32 + c4];
        float4 qv = ((const float4*)bsumsqR)[rep * 32 + c4];
        s.x += sv.x; s.y += sv.y; s.z += sv.z; s.w += sv.w;
        ss.x += qv.x; ss.y += qv.y; ss.z += qv.z; ss.w += qv.w;
    }
    float4 g = ((const float4*)gamma)[c4];
    float4 b = ((const float4*)bbeta)[c4];
    float4 ov = ((const float4*)o)[i];
    float4 hr = ((const float4*)hres)[i];
    float4 r;
    { float mu = s.x * invN, var = ss.x * invN - mu * mu;
      r.x = fmaxf((ov.x - mu) * (g.x * rsqrtf(var + EPS)) + b.x, 0.f) + hr.x; }
    { float mu = s.y * invN, var = ss.y * invN - mu * mu;
      r.y = fmaxf((ov.y - mu) * (g.y * rsqrtf(var + EPS)) + b.y, 0.f) + hr.y; }
    { float mu = s.z * invN, var = ss.z * invN - mu * mu;
      r.z = fmaxf((ov.z - mu) * (g.z * rsqrtf(var + EPS)) + b.z, 0.f) + hr.z; }
    { float mu = s.w * invN, var = ss.w * invN - mu * mu;
      r.w = fmaxf((ov.w - mu) * (g.w * rsqrtf(var + EPS)) + b.w, 0.f) + hr.w; }
    ((float4*)hout)[i] = r;
    if (hout_bf) {
        ushort4 ob = make_ushort4(f2bf(r.x), f2bf(r.y), f2bf(r.z), f2bf(r.w));
        ((ushort4*)hout_bf)[i] = ob;
    }
}

extern "C" void kernel_launch(void* const* d_in, const int* in_sizes, int n_in,
                              void* d_out, int out_size, void* d_ws, size_t ws_size,
                              hipStream_t stream) {
    const float* x     = (const float*)d_in[0];
    const int*   ei    = (const int*)d_in[1];
    const float* ea    = (const float*)d_in[2];
    const float* W_in  = (const float*)d_in[3];
    const float* b_in  = (const float*)d_in[4];
    const float* Wq    = (const float*)d_in[5];
    const float* bq    = (const float*)d_in[6];
    const float* Wk    = (const float*)d_in[7];
    const float* bk    = (const float*)d_in[8];
    const float* Wv    = (const float*)d_in[9];
    const float* bv    = (const float*)d_in[10];
    const float* We    = (const float*)d_in[11];
    const float* Wskip = (const float*)d_in[12];
    const float* bskip = (const float*)d_in[13];
    const float* Wbeta = (const float*)d_in[14];
    const float* bn_g  = (const float*)d_in[15];
    const float* bn_b  = (const float*)d_in[16];

    const int N = in_sizes[0] / 128;
    const int E = in_sizes[1] / 2;

    float* ws = (float*)d_ws;
    unsigned short* Bpack = (unsigned short*)ws;           // 9*16384 bf16 = 73728 floats
    size_t off = 73728;
    unsigned short* xbf  = (unsigned short*)(ws + off);               off += (size_t)N * 64;
    unsigned short* hbf  = (unsigned short*)(ws + off);               off += (size_t)N * 64;
    unsigned short* qbf  = (unsigned short*)(ws + off);               off += (size_t)N * 64;
    unsigned short* kvbf = (unsigned short*)(ws + off);               off += (size_t)N * 128;
    float* h    = ws + off;  off += (size_t)N * 128;
    float* xr   = ws + off;  off += (size_t)N * 128;
    float* attn = ws + off;  off += (size_t)N * 128;
    float* bsumR   = ws + off;  off += 1024;               // 8 replicas x 128
    float* bsumsqR = ws + off;  off += 1024;
    float* csr_w   = ws + off;  off += (size_t)E;
    int* deg     = (int*)(ws + off);
    int* rowptr  = deg + N;
    int* wrptr   = rowptr + (N + 1);
    int* csr_src = wrptr + N;
    int* bsums   = csr_src + E;
    int* boff    = bsums + ((N + 255) / 256 + 1);

    dim3 blk(256);
    int gGemm   = (N + 63) / 64;
    int gNode16 = (N + 15) / 16;
    int gEdge   = (E + 255) / 256;
    int gApply  = (N * 32 + 255) / 256;
    int nbScan  = (N + 255) / 256;

    // ---- weight pack + x convert ----
    pack_w9<<<(9 * 16384 + 255) / 256, blk, 0, stream>>>(
        W_in, Wq, Wk, Wv, Wskip, Wq + 16384, Wk + 16384, Wv + 16384, Wskip + 16384, Bpack);
    f32_to_bf16<<<gApply, blk, 0, stream>>>(x, xbf, N * 32);

    // ---- CSR build ----
    hipMemsetAsync(deg, 0, (size_t)N * sizeof(int), stream);
    csr_hist<<<gEdge, blk, 0, stream>>>(ei, deg, E);
    scan_block_sums<<<nbScan, blk, 0, stream>>>(deg, bsums, N);
    scan_bsums<<<1, blk, 0, stream>>>(bsums, boff, nbScan);
    scan_local<<<nbScan, blk, 0, stream>>>(deg, boff, rowptr, wrptr, N, E);
    csr_fill<<<gEdge, blk, 0, stream>>>(ei, ea, wrptr, csr_src, csr_w, E);

    // ---- input projection (writes h fp32 + hbf bf16) ----
    gemm_mfma<1, 1><<<gGemm, blk, 0, stream>>>(xbf, Bpack + 0 * 16384, b_in, h, hbf, N);

    for (int l = 0; l < 2; ++l) {
        const unsigned short* Bq = Bpack + (size_t)(1 + l * 4 + 0) * 16384;
        const unsigned short* Bk = Bpack + (size_t)(1 + l * 4 + 1) * 16384;
        const unsigned short* Bv = Bpack + (size_t)(1 + l * 4 + 2) * 16384;
        const unsigned short* Bs = Bpack + (size_t)(1 + l * 4 + 3) * 16384;
        gemm_qkvs<<<gGemm, blk, 0, stream>>>(hbf, Bq, Bk, Bv, Bs,
                                             bq + l * 128, bk + l * 128, bv + l * 128, bskip + l * 128,
                                             qbf, kvbf, xr, N);
        hipMemsetAsync(bsumR, 0, 2048 * sizeof(float), stream);
        attn_gather<<<gNode16, blk, 0, stream>>>(qbf, kvbf, xr, rowptr, csr_src, csr_w,
                                                 We + l * 128, Wbeta + l * 384, attn,
                                                 bsumR, bsumsqR, N);
        bn_apply<<<gApply, blk, 0, stream>>>(attn, h, (l == 1) ? (float*)d_out : h,
                                             (l == 0) ? hbf : (unsigned short*)0,
                                             bsumR, bsumsqR, bn_g + l * 128, bn_b + l * 128,
                                             N, 1.0f / (float)N);
    }
}

// Round 13
// 345.366 us; speedup vs baseline: 1.4806x; 1.0024x over previous
//
#include <hip/hip_runtime.h>
#include <hip/hip_bf16.h>
#include <math.h>

#define EPS 1e-5f

typedef __attribute__((ext_vector_type(8))) short bf16x8;
typedef __attribute__((ext_vector_type(4))) float f32x4;

__device__ __forceinline__ unsigned short f2bf(float f) {
    unsigned u = __float_as_uint(f);
    unsigned r = (u + 0x7FFFu + ((u >> 16) & 1u)) >> 16;   // RNE
    return (unsigned short)r;
}
__device__ __forceinline__ unsigned f2bf2(float lo, float hi) {
    return (unsigned)f2bf(lo) | ((unsigned)f2bf(hi) << 16);
}
__device__ __forceinline__ float bf2f(unsigned short u) {
    return __uint_as_float((unsigned)u << 16);
}
__device__ __forceinline__ void bfu2(unsigned u, float& lo, float& hi) {
    lo = __uint_as_float(u << 16);
    hi = __uint_as_float(u & 0xFFFF0000u);
}

// ---------- weight pack: 9 matrices fp32 [128k x 128n] -> bf16 B-fragment order ----------
// fragment (nt,col0) = W column col0*8+nt -> lane's 8 accs are 8 consecutive channels.
__global__ __launch_bounds__(256) void pack_w9(const float* __restrict__ W0, const float* __restrict__ W1,
                                               const float* __restrict__ W2, const float* __restrict__ W3,
                                               const float* __restrict__ W4, const float* __restrict__ W5,
                                               const float* __restrict__ W6, const float* __restrict__ W7,
                                               const float* __restrict__ W8, unsigned short* __restrict__ out) {
    int t = blockIdx.x * 256 + threadIdx.x;
    if (t >= 9 * 16384) return;
    int mat = t >> 14, r = t & 16383;
    const float* W;
    switch (mat) {
        case 0: W = W0; break; case 1: W = W1; break; case 2: W = W2; break;
        case 3: W = W3; break; case 4: W = W4; break; case 5: W = W5; break;
        case 6: W = W6; break; case 7: W = W7; break; default: W = W8; break;
    }
    int j = r & 7, lane = (r >> 3) & 63, nt = (r >> 9) & 7, kc = r >> 12;
    int k = kc * 32 + (lane >> 4) * 8 + j;
    int n = (lane & 15) * 8 + nt;
    out[t] = f2bf(W[k * 128 + n]);
}

// ---------- fp32 -> bf16 elementwise ----------
__global__ __launch_bounds__(256) void f32_to_bf16(const float* __restrict__ in,
                                                   unsigned short* __restrict__ out, int n4) {
    int i = blockIdx.x * 256 + threadIdx.x;
    if (i >= n4) return;
    float4 v = ((const float4*)in)[i];
    ushort4 o = make_ushort4(f2bf(v.x), f2bf(v.y), f2bf(v.z), f2bf(v.w));
    ((ushort4*)out)[i] = o;
}

// ---------- MFMA GEMM (single matrix, coalesced epilogue) ----------
template <int ACT, int WBF>
__global__ __launch_bounds__(256) void gemm_mfma(const unsigned short* __restrict__ Abf,
                                                 const unsigned short* __restrict__ Bp,
                                                 const float* __restrict__ bias,
                                                 float* __restrict__ C,
                                                 unsigned short* __restrict__ Cbf, int M) {
    int wave = threadIdx.x >> 6, lane = threadIdx.x & 63;
    int base = blockIdx.x * 64 + wave * 16;
    int m = lane & 15, kg = lane >> 4;
    int arow = base + m; if (arow >= M) arow = M - 1;
    const unsigned short* Aptr = Abf + (size_t)arow * 128 + kg * 8;
    f32x4 acc[8];
#pragma unroll
    for (int nt = 0; nt < 8; ++nt) acc[nt] = (f32x4)(0.f);
#pragma unroll
    for (int kc = 0; kc < 4; ++kc) {
        bf16x8 a = *(const bf16x8*)(Aptr + kc * 32);
        const unsigned short* bp = Bp + (size_t)kc * 4096 + (size_t)lane * 8;
#pragma unroll
        for (int nt = 0; nt < 8; ++nt) {
            bf16x8 b = *(const bf16x8*)(bp + nt * 512);
            acc[nt] = __builtin_amdgcn_mfma_f32_16x16x32_bf16(a, b, acc[nt], 0, 0, 0);
        }
    }
    int col0 = lane & 15;
    int r0 = base + (lane >> 4) * 4;
    float4 bl = *(const float4*)&bias[col0 * 8];
    float4 bh = *(const float4*)&bias[col0 * 8 + 4];
#pragma unroll
    for (int r = 0; r < 4; ++r) {
        int ro = r0 + r;
        if (ro < M) {
            float v0 = acc[0][r] + bl.x, v1 = acc[1][r] + bl.y;
            float v2 = acc[2][r] + bl.z, v3 = acc[3][r] + bl.w;
            float v4 = acc[4][r] + bh.x, v5 = acc[5][r] + bh.y;
            float v6 = acc[6][r] + bh.z, v7 = acc[7][r] + bh.w;
            if (ACT) {
                v0 = fmaxf(v0, 0.f); v1 = fmaxf(v1, 0.f); v2 = fmaxf(v2, 0.f); v3 = fmaxf(v3, 0.f);
                v4 = fmaxf(v4, 0.f); v5 = fmaxf(v5, 0.f); v6 = fmaxf(v6, 0.f); v7 = fmaxf(v7, 0.f);
            }
            size_t o = (size_t)ro * 128 + col0 * 8;
            *(float4*)&C[o]     = make_float4(v0, v1, v2, v3);
            *(float4*)&C[o + 4] = make_float4(v4, v5, v6, v7);
            if (WBF)
                *(uint4*)&Cbf[o] = make_uint4(f2bf2(v0, v1), f2bf2(v2, v3),
                                              f2bf2(v4, v5), f2bf2(v6, v7));
        }
    }
}

// ---------- 2-matrix fused GEMM: q -> qbf, k -> kvbf[0..128) (both bf16) ----------
// Split from 4-matrix fusion: 64 acc VGPRs instead of 128 -> higher occupancy/MLP.
__global__ __launch_bounds__(256) void gemm_qk(const unsigned short* __restrict__ Abf,
                                               const unsigned short* __restrict__ Bq,
                                               const unsigned short* __restrict__ Bk,
                                               const float* __restrict__ bq,
                                               const float* __restrict__ bk,
                                               unsigned short* __restrict__ qbf,
                                               unsigned short* __restrict__ kvbf, int M) {
    int wave = threadIdx.x >> 6, lane = threadIdx.x & 63;
    int base = blockIdx.x * 64 + wave * 16;
    int m = lane & 15, kg = lane >> 4;
    int arow = base + m; if (arow >= M) arow = M - 1;
    const unsigned short* Aptr = Abf + (size_t)arow * 128 + kg * 8;
    f32x4 aq[8], ak[8];
#pragma unroll
    for (int nt = 0; nt < 8; ++nt) { aq[nt] = (f32x4)(0.f); ak[nt] = (f32x4)(0.f); }
#pragma unroll
    for (int kc = 0; kc < 4; ++kc) {
        bf16x8 a = *(const bf16x8*)(Aptr + kc * 32);
        size_t boff = (size_t)kc * 4096 + (size_t)lane * 8;
#pragma unroll
        for (int nt = 0; nt < 8; ++nt) {
            bf16x8 b0 = *(const bf16x8*)(Bq + boff + nt * 512);
            aq[nt] = __builtin_amdgcn_mfma_f32_16x16x32_bf16(a, b0, aq[nt], 0, 0, 0);
            bf16x8 b1 = *(const bf16x8*)(Bk + boff + nt * 512);
            ak[nt] = __builtin_amdgcn_mfma_f32_16x16x32_bf16(a, b1, ak[nt], 0, 0, 0);
        }
    }
    int col0 = lane & 15;
    int r0 = base + (lane >> 4) * 4;
    float4 bql = *(const float4*)&bq[col0 * 8], bqh = *(const float4*)&bq[col0 * 8 + 4];
    float4 bkl = *(const float4*)&bk[col0 * 8], bkh = *(const float4*)&bk[col0 * 8 + 4];
#pragma unroll
    for (int r = 0; r < 4; ++r) {
        int ro = r0 + r;
        if (ro < M) {
            size_t qo = (size_t)ro * 128 + col0 * 8;
            size_t kvo = (size_t)ro * 256 + col0 * 8;
            *(uint4*)&qbf[qo] = make_uint4(
                f2bf2(aq[0][r] + bql.x, aq[1][r] + bql.y), f2bf2(aq[2][r] + bql.z, aq[3][r] + bql.w),
                f2bf2(aq[4][r] + bqh.x, aq[5][r] + bqh.y), f2bf2(aq[6][r] + bqh.z, aq[7][r] + bqh.w));
            *(uint4*)&kvbf[kvo] = make_uint4(
                f2bf2(ak[0][r] + bkl.x, ak[1][r] + bkl.y), f2bf2(ak[2][r] + bkl.z, ak[3][r] + bkl.w),
                f2bf2(ak[4][r] + bkh.x, ak[5][r] + bkh.y), f2bf2(ak[6][r] + bkh.z, ak[7][r] + bkh.w));
        }
    }
}

// ---------- 2-matrix fused GEMM: v -> kvbf[128..256) (bf16), skip -> xr (fp32) ----------
__global__ __launch_bounds__(256) void gemm_vs(const unsigned short* __restrict__ Abf,
                                               const unsigned short* __restrict__ Bv,
                                               const unsigned short* __restrict__ Bs,
                                               const float* __restrict__ bv,
                                               const float* __restrict__ bs,
                                               unsigned short* __restrict__ kvbf,
                                               float* __restrict__ xr, int M) {
    int wave = threadIdx.x >> 6, lane = threadIdx.x & 63;
    int base = blockIdx.x * 64 + wave * 16;
    int m = lane & 15, kg = lane >> 4;
    int arow = base + m; if (arow >= M) arow = M - 1;
    const unsigned short* Aptr = Abf + (size_t)arow * 128 + kg * 8;
    f32x4 av[8], as_[8];
#pragma unroll
    for (int nt = 0; nt < 8; ++nt) { av[nt] = (f32x4)(0.f); as_[nt] = (f32x4)(0.f); }
#pragma unroll
    for (int kc = 0; kc < 4; ++kc) {
        bf16x8 a = *(const bf16x8*)(Aptr + kc * 32);
        size_t boff = (size_t)kc * 4096 + (size_t)lane * 8;
#pragma unroll
        for (int nt = 0; nt < 8; ++nt) {
            bf16x8 b2 = *(const bf16x8*)(Bv + boff + nt * 512);
            av[nt] = __builtin_amdgcn_mfma_f32_16x16x32_bf16(a, b2, av[nt], 0, 0, 0);
            bf16x8 b3 = *(const bf16x8*)(Bs + boff + nt * 512);
            as_[nt] = __builtin_amdgcn_mfma_f32_16x16x32_bf16(a, b3, as_[nt], 0, 0, 0);
        }
    }
    int col0 = lane & 15;
    int r0 = base + (lane >> 4) * 4;
    float4 bvl = *(const float4*)&bv[col0 * 8], bvh = *(const float4*)&bv[col0 * 8 + 4];
    float4 bsl = *(const float4*)&bs[col0 * 8], bsh = *(const float4*)&bs[col0 * 8 + 4];
#pragma unroll
    for (int r = 0; r < 4; ++r) {
        int ro = r0 + r;
        if (ro < M) {
            size_t qo = (size_t)ro * 128 + col0 * 8;
            size_t kvo = (size_t)ro * 256 + 128 + col0 * 8;
            *(uint4*)&kvbf[kvo] = make_uint4(
                f2bf2(av[0][r] + bvl.x, av[1][r] + bvl.y), f2bf2(av[2][r] + bvl.z, av[3][r] + bvl.w),
                f2bf2(av[4][r] + bvh.x, av[5][r] + bvh.y), f2bf2(av[6][r] + bvh.z, av[7][r] + bvh.w));
            *(float4*)&xr[qo]     = make_float4(as_[0][r] + bsl.x, as_[1][r] + bsl.y,
                                                as_[2][r] + bsl.z, as_[3][r] + bsl.w);
            *(float4*)&xr[qo + 4] = make_float4(as_[4][r] + bsh.x, as_[5][r] + bsh.y,
                                                as_[6][r] + bsh.z, as_[7][r] + bsh.w);
        }
    }
}

// ---------- CSR build ----------
__global__ __launch_bounds__(256) void csr_hist(const int* __restrict__ ei,
                                                int* __restrict__ deg, int E) {
    int e = blockIdx.x * 256 + threadIdx.x;
    if (e < E) atomicAdd(&deg[ei[E + e]], 1);
}

__global__ __launch_bounds__(256) void scan_block_sums(const int* __restrict__ deg,
                                                       int* __restrict__ bsums, int N) {
    __shared__ int sd[256];
    int i = blockIdx.x * 256 + threadIdx.x;
    sd[threadIdx.x] = (i < N) ? deg[i] : 0;
    __syncthreads();
    for (int off = 128; off > 0; off >>= 1) {
        if (threadIdx.x < off) sd[threadIdx.x] += sd[threadIdx.x + off];
        __syncthreads();
    }
    if (threadIdx.x == 0) bsums[blockIdx.x] = sd[0];
}

__global__ __launch_bounds__(256) void scan_bsums(const int* __restrict__ bsums,
                                                  int* __restrict__ boff, int nb) {
    __shared__ int sd[256];
    int tid = threadIdx.x;
    int per = (nb + 255) / 256;
    int start = tid * per;
    int s = 0;
    for (int i = 0; i < per; ++i) {
        int idx = start + i;
        if (idx < nb) s += bsums[idx];
    }
    int my = s;
    sd[tid] = s;
    __syncthreads();
    for (int off = 1; off < 256; off <<= 1) {
        int t = (tid >= off) ? sd[tid - off] : 0;
        __syncthreads();
        sd[tid] += t;
        __syncthreads();
    }
    int run = sd[tid] - my;
    for (int i = 0; i < per; ++i) {
        int idx = start + i;
        if (idx < nb) {
            boff[idx] = run;
            run += bsums[idx];
        }
    }
}

__global__ __launch_bounds__(256) void scan_local(const int* __restrict__ deg,
                                                  const int* __restrict__ boff,
                                                  int* __restrict__ rowptr,
                                                  int* __restrict__ wrptr, int N, int E) {
    __shared__ int sd[256];
    int i = blockIdx.x * 256 + threadIdx.x;
    int v = (i < N) ? deg[i] : 0;
    sd[threadIdx.x] = v;
    __syncthreads();
    for (int off = 1; off < 256; off <<= 1) {
        int t = (threadIdx.x >= off) ? sd[threadIdx.x - off] : 0;
        __syncthreads();
        sd[threadIdx.x] += t;
        __syncthreads();
    }
    if (i < N) {
        int excl = sd[threadIdx.x] - v + boff[blockIdx.x];
        rowptr[i] = excl;
        wrptr[i] = excl;
        if (i == N - 1) rowptr[N] = E;
    }
}

__global__ __launch_bounds__(256) void csr_fill(const int* __restrict__ ei,
                                                const float* __restrict__ ea,
                                                int* __restrict__ wrptr,
                                                int* __restrict__ csr_src,
                                                float* __restrict__ csr_w, int E) {
    int e = blockIdx.x * 256 + threadIdx.x;
    if (e >= E) return;
    int tgt = ei[E + e];
    int pos = atomicAdd(&wrptr[tgt], 1);
    csr_src[pos] = ei[e];
    csr_w[pos] = ea[e];
}

// ---------- attention gather v4: 16 lanes/node + fused BN stats ----------
__global__ __launch_bounds__(256) void attn_gather(const unsigned short* __restrict__ qbf,
                                                   const unsigned short* __restrict__ kvbf,
                                                   const float* __restrict__ xr,
                                                   const int* __restrict__ rowptr,
                                                   const int* __restrict__ csr_src,
                                                   const float* __restrict__ csr_w,
                                                   const float* __restrict__ Wel,
                                                   const float* __restrict__ Wb,
                                                   float* __restrict__ out,
                                                   float* __restrict__ bsumR,
                                                   float* __restrict__ bsumsqR, int N) {
    __shared__ float sdS[4][128];
    __shared__ float sdQ[4][128];
    int tid = threadIdx.x;
    int n = blockIdx.x * 16 + (tid >> 4);
    int sl = tid & 15;
    int wave = tid >> 6, lane = tid & 63;
    bool live = (n < N);
    int nn = live ? n : (N - 1);

    uint4 qu = ((const uint4*)(qbf + (size_t)nn * 128))[sl];
    float qf[8];
    bfu2(qu.x, qf[0], qf[1]); bfu2(qu.y, qf[2], qf[3]);
    bfu2(qu.z, qf[4], qf[5]); bfu2(qu.w, qf[6], qf[7]);
    float wef[8];
    {
        float4 w0 = ((const float4*)Wel)[sl * 2];
        float4 w1 = ((const float4*)Wel)[sl * 2 + 1];
        wef[0] = w0.x; wef[1] = w0.y; wef[2] = w0.z; wef[3] = w0.w;
        wef[4] = w1.x; wef[5] = w1.y; wef[6] = w1.z; wef[7] = w1.w;
    }
    float qwe = 0.f;
#pragma unroll
    for (int c = 0; c < 8; ++c) qwe += qf[c] * wef[c];
    qwe += __shfl_xor(qwe, 1);
    qwe += __shfl_xor(qwe, 2);

    float l = 0.f;
    float acc[8];
#pragma unroll
    for (int c = 0; c < 8; ++c) acc[c] = 0.f;

    int beg = live ? rowptr[nn] : 0;
    int end = live ? rowptr[nn + 1] : 0;
    int i = beg;
    if (i < end) {
        float w = csr_w[i];
        const uint4* kvr = (const uint4*)(kvbf + (size_t)csr_src[i] * 256);
        uint4 ku = kvr[sl];
        uint4 vu = kvr[16 + sl];
        for (;;) {
            float wc = w;
            uint4 kuc = ku, vuc = vu;
            ++i;
            bool more = (i < end);
            if (more) {
                float w2 = csr_w[i];
                const uint4* kvr2 = (const uint4*)(kvbf + (size_t)csr_src[i] * 256);
                ku = kvr2[sl];
                vu = kvr2[16 + sl];
                w = w2;
            }
            float kf[8];
            bfu2(kuc.x, kf[0], kf[1]); bfu2(kuc.y, kf[2], kf[3]);
            bfu2(kuc.z, kf[4], kf[5]); bfu2(kuc.w, kf[6], kf[7]);
            float d = 0.f;
#pragma unroll
            for (int c = 0; c < 8; ++c) d += qf[c] * kf[c];
            d += __shfl_xor(d, 1);
            d += __shfl_xor(d, 2);
            float p = __expf((d + wc * qwe) * 0.17677669529663687f);
            l += p;
            float vf[8];
            bfu2(vuc.x, vf[0], vf[1]); bfu2(vuc.y, vf[2], vf[3]);
            bfu2(vuc.z, vf[4], vf[5]); bfu2(vuc.w, vf[6], vf[7]);
#pragma unroll
            for (int c = 0; c < 8; ++c)
                acc[c] += p * (vf[c] + wc * wef[c]);
            if (!more) break;
        }
    }

    float inv = (l > 0.f) ? 1.f / l : 0.f;
    float ox[8];
#pragma unroll
    for (int c = 0; c < 8; ++c) ox[c] = acc[c] * inv;

    const float* xrow = xr + (size_t)nn * 128;
    float4 a0 = ((const float4*)xrow)[sl * 2];
    float4 a1 = ((const float4*)xrow)[sl * 2 + 1];
    float xv[8] = {a0.x, a0.y, a0.z, a0.w, a1.x, a1.y, a1.z, a1.w};
    float4 b0 = ((const float4*)Wb)[sl * 2];
    float4 b1 = ((const float4*)Wb)[sl * 2 + 1];
    float4 c0 = ((const float4*)(Wb + 128))[sl * 2];
    float4 c1 = ((const float4*)(Wb + 128))[sl * 2 + 1];
    float4 d0 = ((const float4*)(Wb + 256))[sl * 2];
    float4 d1 = ((const float4*)(Wb + 256))[sl * 2 + 1];
    float wb0[8] = {b0.x, b0.y, b0.z, b0.w, b1.x, b1.y, b1.z, b1.w};
    float wb1[8] = {c0.x, c0.y, c0.z, c0.w, c1.x, c1.y, c1.z, c1.w};
    float wb2[8] = {d0.x, d0.y, d0.z, d0.w, d1.x, d1.y, d1.z, d1.w};
    float part = 0.f;
#pragma unroll
    for (int c = 0; c < 8; ++c)
        part += ox[c] * wb0[c] + xv[c] * wb1[c] + (ox[c] - xv[c]) * wb2[c];
    part += __shfl_xor(part, 1); part += __shfl_xor(part, 2);
    part += __shfl_xor(part, 4); part += __shfl_xor(part, 8);
    float beta = 1.f / (1.f + __expf(-part));

    float r[8];
#pragma unroll
    for (int c = 0; c < 8; ++c)
        r[c] = beta * xv[c] + (1.f - beta) * ox[c];

    if (live) {
        ((float4*)(out + (size_t)n * 128))[sl * 2] =
            make_float4(r[0], r[1], r[2], r[3]);
        ((float4*)(out + (size_t)n * 128))[sl * 2 + 1] =
            make_float4(r[4], r[5], r[6], r[7]);
    }

    // ---- fused BN stats ----
    float s8[8], q8[8];
#pragma unroll
    for (int c = 0; c < 8; ++c) {
        s8[c] = live ? r[c] : 0.f;
        q8[c] = live ? r[c] * r[c] : 0.f;
    }
#pragma unroll
    for (int c = 0; c < 8; ++c) {
        s8[c] += __shfl_xor(s8[c], 16); s8[c] += __shfl_xor(s8[c], 32);
        q8[c] += __shfl_xor(q8[c], 16); q8[c] += __shfl_xor(q8[c], 32);
    }
    if ((lane >> 4) == 0) {
#pragma unroll
        for (int c = 0; c < 8; ++c) {
            sdS[wave][sl * 8 + c] = s8[c];
            sdQ[wave][sl * 8 + c] = q8[c];
        }
    }
    __syncthreads();
    if (tid < 128) {
        float s = sdS[0][tid] + sdS[1][tid] + sdS[2][tid] + sdS[3][tid];
        float q = sdQ[0][tid] + sdQ[1][tid] + sdQ[2][tid] + sdQ[3][tid];
        int rep = blockIdx.x & 7;
        atomicAdd(&bsumR[rep * 128 + tid], s);
        atomicAdd(&bsumsqR[rep * 128 + tid], q);
    }
}

// ---------- BN apply + ReLU + residual (+ optional bf16 side-write), 8-replica stats ----------
__global__ __launch_bounds__(256) void bn_apply(const float* __restrict__ o,
                                                const float* __restrict__ hres,
                                                float* __restrict__ hout,
                                                unsigned short* __restrict__ hout_bf,
                                                const float* __restrict__ bsumR,
                                                const float* __restrict__ bsumsqR,
                                                const float* __restrict__ gamma,
                                                const float* __restrict__ bbeta,
                                                int N, float invN) {
    int i = blockIdx.x * 256 + threadIdx.x;
    if (i >= N * 32) return;
    int c4 = i & 31;
    float4 s = make_float4(0.f, 0.f, 0.f, 0.f), ss = s;
#pragma unroll
    for (int rep = 0; rep < 8; ++rep) {
        float4 sv = ((const float4*)bsumR)[rep * 32 + c4];
        float4 qv = ((const float4*)bsumsqR)[rep * 32 + c4];
        s.x += sv.x; s.y += sv.y; s.z += sv.z; s.w += sv.w;
        ss.x += qv.x; ss.y += qv.y; ss.z += qv.z; ss.w += qv.w;
    }
    float4 g = ((const float4*)gamma)[c4];
    float4 b = ((const float4*)bbeta)[c4];
    float4 ov = ((const float4*)o)[i];
    float4 hr = ((const float4*)hres)[i];
    float4 r;
    { float mu = s.x * invN, var = ss.x * invN - mu * mu;
      r.x = fmaxf((ov.x - mu) * (g.x * rsqrtf(var + EPS)) + b.x, 0.f) + hr.x; }
    { float mu = s.y * invN, var = ss.y * invN - mu * mu;
      r.y = fmaxf((ov.y - mu) * (g.y * rsqrtf(var + EPS)) + b.y, 0.f) + hr.y; }
    { float mu = s.z * invN, var = ss.z * invN - mu * mu;
      r.z = fmaxf((ov.z - mu) * (g.z * rsqrtf(var + EPS)) + b.z, 0.f) + hr.z; }
    { float mu = s.w * invN, var = ss.w * invN - mu * mu;
      r.w = fmaxf((ov.w - mu) * (g.w * rsqrtf(var + EPS)) + b.w, 0.f) + hr.w; }
    ((float4*)hout)[i] = r;
    if (hout_bf) {
        ushort4 ob = make_ushort4(f2bf(r.x), f2bf(r.y), f2bf(r.z), f2bf(r.w));
        ((ushort4*)hout_bf)[i] = ob;
    }
}

extern "C" void kernel_launch(void* const* d_in, const int* in_sizes, int n_in,
                              void* d_out, int out_size, void* d_ws, size_t ws_size,
                              hipStream_t stream) {
    const float* x     = (const float*)d_in[0];
    const int*   ei    = (const int*)d_in[1];
    const float* ea    = (const float*)d_in[2];
    const float* W_in  = (const float*)d_in[3];
    const float* b_in  = (const float*)d_in[4];
    const float* Wq    = (const float*)d_in[5];
    const float* bq    = (const float*)d_in[6];
    const float* Wk    = (const float*)d_in[7];
    const float* bk    = (const float*)d_in[8];
    const float* Wv    = (const float*)d_in[9];
    const float* bv    = (const float*)d_in[10];
    const float* We    = (const float*)d_in[11];
    const float* Wskip = (const float*)d_in[12];
    const float* bskip = (const float*)d_in[13];
    const float* Wbeta = (const float*)d_in[14];
    const float* bn_g  = (const float*)d_in[15];
    const float* bn_b  = (const float*)d_in[16];

    const int N = in_sizes[0] / 128;
    const int E = in_sizes[1] / 2;

    float* ws = (float*)d_ws;
    unsigned short* Bpack = (unsigned short*)ws;           // 9*16384 bf16 = 73728 floats
    size_t off = 73728;
    unsigned short* xbf  = (unsigned short*)(ws + off);               off += (size_t)N * 64;
    unsigned short* hbf  = (unsigned short*)(ws + off);               off += (size_t)N * 64;
    unsigned short* qbf  = (unsigned short*)(ws + off);               off += (size_t)N * 64;
    unsigned short* kvbf = (unsigned short*)(ws + off);               off += (size_t)N * 128;
    float* h    = ws + off;  off += (size_t)N * 128;
    float* xr   = ws + off;  off += (size_t)N * 128;
    float* attn = ws + off;  off += (size_t)N * 128;
    float* bsumR   = ws + off;  off += 1024;               // 8 replicas x 128
    float* bsumsqR = ws + off;  off += 1024;
    float* csr_w   = ws + off;  off += (size_t)E;
    int* deg     = (int*)(ws + off);
    int* rowptr  = deg + N;
    int* wrptr   = rowptr + (N + 1);
    int* csr_src = wrptr + N;
    int* bsums   = csr_src + E;
    int* boff    = bsums + ((N + 255) / 256 + 1);

    dim3 blk(256);
    int gGemm   = (N + 63) / 64;
    int gNode16 = (N + 15) / 16;
    int gEdge   = (E + 255) / 256;
    int gApply  = (N * 32 + 255) / 256;
    int nbScan  = (N + 255) / 256;

    // ---- weight pack + x convert ----
    pack_w9<<<(9 * 16384 + 255) / 256, blk, 0, stream>>>(
        W_in, Wq, Wk, Wv, Wskip, Wq + 16384, Wk + 16384, Wv + 16384, Wskip + 16384, Bpack);
    f32_to_bf16<<<gApply, blk, 0, stream>>>(x, xbf, N * 32);

    // ---- CSR build ----
    hipMemsetAsync(deg, 0, (size_t)N * sizeof(int), stream);
    csr_hist<<<gEdge, blk, 0, stream>>>(ei, deg, E);
    scan_block_sums<<<nbScan, blk, 0, stream>>>(deg, bsums, N);
    scan_bsums<<<1, blk, 0, stream>>>(bsums, boff, nbScan);
    scan_local<<<nbScan, blk, 0, stream>>>(deg, boff, rowptr, wrptr, N, E);
    csr_fill<<<gEdge, blk, 0, stream>>>(ei, ea, wrptr, csr_src, csr_w, E);

    // ---- input projection (writes h fp32 + hbf bf16) ----
    gemm_mfma<1, 1><<<gGemm, blk, 0, stream>>>(xbf, Bpack + 0 * 16384, b_in, h, hbf, N);

    for (int l = 0; l < 2; ++l) {
        const unsigned short* Bq = Bpack + (size_t)(1 + l * 4 + 0) * 16384;
        const unsigned short* Bk = Bpack + (size_t)(1 + l * 4 + 1) * 16384;
        const unsigned short* Bv = Bpack + (size_t)(1 + l * 4 + 2) * 16384;
        const unsigned short* Bs = Bpack + (size_t)(1 + l * 4 + 3) * 16384;
        gemm_qk<<<gGemm, blk, 0, stream>>>(hbf, Bq, Bk, bq + l * 128, bk + l * 128,
                                           qbf, kvbf, N);
        gemm_vs<<<gGemm, blk, 0, stream>>>(hbf, Bv, Bs, bv + l * 128, bskip + l * 128,
                                           kvbf, xr, N);
        hipMemsetAsync(bsumR, 0, 2048 * sizeof(float), stream);
        attn_gather<<<gNode16, blk, 0, stream>>>(qbf, kvbf, xr, rowptr, csr_src, csr_w,
                                                 We + l * 128, Wbeta + l * 384, attn,
                                                 bsumR, bsumsqR, N);
        bn_apply<<<gApply, blk, 0, stream>>>(attn, h, (l == 1) ? (float*)d_out : h,
                                             (l == 0) ? hbf : (unsigned short*)0,
                                             bsumR, bsumsqR, bn_g + l * 128, bn_b + l * 128,
                                             N, 1.0f / (float)N);
    }
}